// Round 5
// baseline (3052.520 us; speedup 1.0000x reference)
//
#include <hip/hip_runtime.h>
#include <hip/hip_bf16.h>

#define BH 16
#define NTOK 8192
#define NHEAD 8
#define DH 64
#define MLM 256
#define QSCALE 0.125f

// ---------------- zero fill
__global__ __launch_bounds__(256) void k_zero(float* __restrict__ p, int n){
  int i = blockIdx.x * 256 + threadIdx.x;
  if (i < n) p[i] = 0.f;
}

// ---------------- QKV projection: x[16384,512]f32 @ wqkv[512,1536]f32 -> q,k,v f32 [bh][n][dh]
__global__ __launch_bounds__(256) void k_qkv(const float* __restrict__ x,
                                             const float* __restrict__ wqkv,
                                             float* __restrict__ q,
                                             float* __restrict__ k,
                                             float* __restrict__ v){
  const int n0 = blockIdx.x * 64;   // over 1536
  const int m0 = blockIdx.y * 64;   // over 16384
  __shared__ float As[16][64];
  __shared__ float Bs[16][64];
  const int tid = threadIdx.x, ty = tid >> 4, tx = tid & 15;
  const int lm = tid >> 2, lk = (tid & 3) << 2;
  const int lk2 = tid >> 4, ln = (tid & 15) << 2;
  float acc[4][4] = {};
  for (int k0 = 0; k0 < 512; k0 += 16){
    float4 a4 = *(const float4*)(x + (size_t)(m0 + lm) * 512 + k0 + lk);
    As[lk+0][lm] = a4.x; As[lk+1][lm] = a4.y; As[lk+2][lm] = a4.z; As[lk+3][lm] = a4.w;
    float4 b4 = *(const float4*)(wqkv + (size_t)(k0 + lk2) * 1536 + n0 + ln);
    Bs[lk2][ln+0] = b4.x; Bs[lk2][ln+1] = b4.y; Bs[lk2][ln+2] = b4.z; Bs[lk2][ln+3] = b4.w;
    __syncthreads();
#pragma unroll
    for (int kk = 0; kk < 16; kk++){
      float a[4], bv[4];
#pragma unroll
      for (int r = 0; r < 4; r++) a[r] = As[kk][ty*4 + r];
#pragma unroll
      for (int c = 0; c < 4; c++) bv[c] = Bs[kk][tx*4 + c];
#pragma unroll
      for (int r = 0; r < 4; r++)
#pragma unroll
        for (int c = 0; c < 4; c++) acc[r][c] += a[r] * bv[c];
    }
    __syncthreads();
  }
#pragma unroll
  for (int r = 0; r < 4; r++){
    const int row = m0 + ty*4 + r;
    const int bb = row >> 13, i = row & 8191;
#pragma unroll
    for (int c = 0; c < 4; c++){
      const int col = n0 + tx*4 + c;
      const int which = col >> 9;
      const int cc = col & 511;
      const int h = cc >> 6, d = cc & 63;
      const size_t off = (((size_t)(bb * NHEAD + h)) * NTOK + i) * DH + d;
      float val = acc[r][c];
      if (which == 0)      q[off] = val * QSCALE;
      else if (which == 1) k[off] = val;
      else                 v[off] = val;
    }
  }
}

// ---------------- landmark means: mean over groups of 32 tokens (fp32)
__global__ __launch_bounds__(64) void k_land(const float* __restrict__ src, float* __restrict__ dst){
  const int bh = blockIdx.x >> 8;
  const int j  = blockIdx.x & 255;
  const int d  = threadIdx.x;
  const float* p = src + ((size_t)bh * NTOK + (size_t)j * 32) * DH + d;
  float s = 0.f;
#pragma unroll
  for (int t = 0; t < 32; t++) s += p[t * DH];
  dst[((size_t)bh * MLM + j) * DH + d] = s * (1.f / 32.f);
}

// ---------------- sim2 = ql @ kl^T (fp32, K=64), batched [bh][256][256]
__global__ __launch_bounds__(256) void k_sim2(const float* __restrict__ qlf,
                                              const float* __restrict__ klf,
                                              float* __restrict__ C){
  const int bh = blockIdx.z;
  const float* Ab = qlf + (size_t)bh * MLM * DH;
  const float* Bb = klf + (size_t)bh * MLM * DH;
  float* Cb = C + (size_t)bh * MLM * MLM;
  const int n0 = blockIdx.x * 64;
  const int m0 = blockIdx.y * 64;
  __shared__ float As[16][64];
  __shared__ float Bs[16][64];
  const int tid = threadIdx.x, ty = tid >> 4, tx = tid & 15;
  const int lm = tid >> 2, lk = (tid & 3) << 2;
  float acc[4][4] = {};
  for (int k0 = 0; k0 < 64; k0 += 16){
    float4 a4 = *(const float4*)(Ab + (size_t)(m0 + lm) * DH + k0 + lk);
    As[lk+0][lm] = a4.x; As[lk+1][lm] = a4.y; As[lk+2][lm] = a4.z; As[lk+3][lm] = a4.w;
    float4 b4 = *(const float4*)(Bb + (size_t)(n0 + lm) * DH + k0 + lk);
    Bs[lk+0][lm] = b4.x; Bs[lk+1][lm] = b4.y; Bs[lk+2][lm] = b4.z; Bs[lk+3][lm] = b4.w;
    __syncthreads();
#pragma unroll
    for (int kk = 0; kk < 16; kk++){
      float a[4], bv[4];
#pragma unroll
      for (int r = 0; r < 4; r++) a[r] = As[kk][ty*4 + r];
#pragma unroll
      for (int c = 0; c < 4; c++) bv[c] = Bs[kk][tx*4 + c];
#pragma unroll
      for (int r = 0; r < 4; r++)
#pragma unroll
        for (int c = 0; c < 4; c++) acc[r][c] += a[r] * bv[c];
    }
    __syncthreads();
  }
#pragma unroll
  for (int r = 0; r < 4; r++)
#pragma unroll
    for (int c = 0; c < 4; c++)
      Cb[(size_t)(m0 + ty*4 + r) * MLM + n0 + tx*4 + c] = acc[r][c];
}

// ---------------- row softmax over 256
__global__ __launch_bounds__(256) void k_softmax256(const float* __restrict__ in, float* __restrict__ outp){
  const int row = blockIdx.x;
  const int t = threadIdx.x;
  float v = in[(size_t)row * 256 + t];
  __shared__ float red[256];
  red[t] = v; __syncthreads();
  for (int o = 128; o > 0; o >>= 1){ if (t < o) red[t] = fmaxf(red[t], red[t+o]); __syncthreads(); }
  float mx = red[0]; __syncthreads();
  float e = expf(v - mx);
  red[t] = e; __syncthreads();
  for (int o = 128; o > 0; o >>= 1){ if (t < o) red[t] += red[t+o]; __syncthreads(); }
  outp[(size_t)row * 256 + t] = e / red[0];
}

// ---------------- per-batch row/col abs-sum maxima partials
__global__ __launch_bounds__(256) void k_colrow(const float* __restrict__ a2, float* __restrict__ part){
  const int bh = blockIdx.x;
  const int t = threadIdx.x;
  const float* p = a2 + (size_t)bh * 65536;
  float rs = 0.f, cs = 0.f;
  for (int j = 0; j < 256; j++) rs += fabsf(p[(size_t)t * 256 + j]);
  for (int i = 0; i < 256; i++) cs += fabsf(p[(size_t)i * 256 + t]);
  __shared__ float r1[256], r2[256];
  r1[t] = rs; r2[t] = cs; __syncthreads();
  for (int o = 128; o > 0; o >>= 1){
    if (t < o){ r1[t] = fmaxf(r1[t], r1[t+o]); r2[t] = fmaxf(r2[t], r2[t+o]); }
    __syncthreads();
  }
  if (t == 0){ part[bh] = r1[0]; part[16 + bh] = r2[0]; }
}

// ---------------- z0 = a2^T * (1/(col*row)), GLOBAL maxima over all bh
__global__ __launch_bounds__(256) void k_z0(const float* __restrict__ a2, const float* __restrict__ part,
                                            float* __restrict__ z){
  const int bh = blockIdx.x >> 8;
  const int i  = blockIdx.x & 255;
  const int j  = threadIdx.x;
  float m1 = 0.f, m2 = 0.f;
#pragma unroll
  for (int t = 0; t < 16; t++){ m1 = fmaxf(m1, part[t]); m2 = fmaxf(m2, part[16 + t]); }
  const float sc = 1.f / (m1 * m2);
  z[((size_t)bh * 256 + i) * 256 + j] = a2[((size_t)bh * 256 + j) * 256 + i] * sc;
}

// ---------------- batched 256^3 GEMM with pinv epilogue: C = s0*(c0*D - A@B)
__global__ __launch_bounds__(256) void k_gemm256(const float* __restrict__ A, const float* __restrict__ Bm,
                                                 const float* __restrict__ D, float* __restrict__ C,
                                                 float c0, float s0){
  const int bh = blockIdx.y;
  const int mt = blockIdx.x >> 2, nt = blockIdx.x & 3;
  const size_t bo = (size_t)bh * 65536;
  const float* Ab = A + bo; const float* Bb = Bm + bo;
  const float* Db = D + bo; float* Cb = C + bo;
  __shared__ float As[16][64];
  __shared__ float Bs[16][64];
  const int tid = threadIdx.x, ty = tid >> 4, tx = tid & 15;
  const int lm = tid >> 2, lk = (tid & 3) << 2;
  const int lk2 = tid >> 4, ln = (tid & 15) << 2;
  const int m0 = mt * 64, n0 = nt * 64;
  float acc[4][4] = {};
  for (int k0 = 0; k0 < 256; k0 += 16){
    float4 a4 = *(const float4*)(Ab + (size_t)(m0 + lm) * 256 + k0 + lk);
    As[lk+0][lm] = a4.x; As[lk+1][lm] = a4.y; As[lk+2][lm] = a4.z; As[lk+3][lm] = a4.w;
    float4 b4 = *(const float4*)(Bb + (size_t)(k0 + lk2) * 256 + n0 + ln);
    *(float4*)&Bs[lk2][ln] = b4;
    __syncthreads();
#pragma unroll
    for (int kk = 0; kk < 16; kk++){
      float a[4], bv[4];
#pragma unroll
      for (int r = 0; r < 4; r++) a[r] = As[kk][ty*4 + r];
#pragma unroll
      for (int c = 0; c < 4; c++) bv[c] = Bs[kk][tx*4 + c];
#pragma unroll
      for (int r = 0; r < 4; r++)
#pragma unroll
        for (int c = 0; c < 4; c++) acc[r][c] += a[r] * bv[c];
    }
    __syncthreads();
  }
#pragma unroll
  for (int r = 0; r < 4; r++)
#pragma unroll
    for (int c = 0; c < 4; c++){
      const size_t idx = (size_t)(m0 + ty*4 + r) * 256 + n0 + tx*4 + c;
      Cb[idx] = s0 * (c0 * Db[idx] - acc[r][c]);
    }
}

// ---------------- sim3 slice = ql @ k^T (fp32) [256 x 8192], one bh
__global__ __launch_bounds__(256) void k_sim3(const float* __restrict__ Aq,
                                              const float* __restrict__ Bk,
                                              float* __restrict__ C){
  const int n0 = blockIdx.x * 64;   // over 8192
  const int m0 = blockIdx.y * 64;   // over 256
  __shared__ float As[16][64];
  __shared__ float Bs[16][64];
  const int tid = threadIdx.x, ty = tid >> 4, tx = tid & 15;
  const int lm = tid >> 2, lk = (tid & 3) << 2;
  float acc[4][4] = {};
  for (int k0 = 0; k0 < 64; k0 += 16){
    float4 a4 = *(const float4*)(Aq + (size_t)(m0 + lm) * DH + k0 + lk);
    As[lk+0][lm] = a4.x; As[lk+1][lm] = a4.y; As[lk+2][lm] = a4.z; As[lk+3][lm] = a4.w;
    float4 b4 = *(const float4*)(Bk + (size_t)(n0 + lm) * DH + k0 + lk);
    Bs[lk+0][lm] = b4.x; Bs[lk+1][lm] = b4.y; Bs[lk+2][lm] = b4.z; Bs[lk+3][lm] = b4.w;
    __syncthreads();
#pragma unroll
    for (int kk = 0; kk < 16; kk++){
      float a[4], bv[4];
#pragma unroll
      for (int r = 0; r < 4; r++) a[r] = As[kk][ty*4 + r];
#pragma unroll
      for (int c = 0; c < 4; c++) bv[c] = Bs[kk][tx*4 + c];
#pragma unroll
      for (int r = 0; r < 4; r++)
#pragma unroll
        for (int c = 0; c < 4; c++) acc[r][c] += a[r] * bv[c];
    }
    __syncthreads();
  }
#pragma unroll
  for (int r = 0; r < 4; r++)
#pragma unroll
    for (int c = 0; c < 4; c++)
      C[(size_t)(m0 + ty*4 + r) * NTOK + n0 + tx*4 + c] = acc[r][c];
}

// ---------------- row softmax over 8192, in place (one bh slice, 256 rows)
__global__ __launch_bounds__(256) void k_softmax_n(float* __restrict__ p){
  float* row = p + (size_t)blockIdx.x * 8192;
  const int t = threadIdx.x;
  float4 vals[8];
  float mx = -1e30f;
#pragma unroll
  for (int r = 0; r < 8; r++){
    vals[r] = ((const float4*)row)[t + r * 256];
    mx = fmaxf(mx, fmaxf(fmaxf(vals[r].x, vals[r].y), fmaxf(vals[r].z, vals[r].w)));
  }
  __shared__ float red[256];
  red[t] = mx; __syncthreads();
  for (int o = 128; o > 0; o >>= 1){ if (t < o) red[t] = fmaxf(red[t], red[t+o]); __syncthreads(); }
  mx = red[0]; __syncthreads();
  float s = 0.f;
#pragma unroll
  for (int r = 0; r < 8; r++){
    vals[r].x = expf(vals[r].x - mx); vals[r].y = expf(vals[r].y - mx);
    vals[r].z = expf(vals[r].z - mx); vals[r].w = expf(vals[r].w - mx);
    s += vals[r].x + vals[r].y + vals[r].z + vals[r].w;
  }
  red[t] = s; __syncthreads();
  for (int o = 128; o > 0; o >>= 1){ if (t < o) red[t] += red[t+o]; __syncthreads(); }
  const float inv = 1.f / red[0];
#pragma unroll
  for (int r = 0; r < 8; r++){
    float4 w; w.x = vals[r].x * inv; w.y = vals[r].y * inv; w.z = vals[r].z * inv; w.w = vals[r].w * inv;
    ((float4*)row)[t + r * 256] = w;
  }
}

// ---------------- av_slice += attn3_slice @ v_slice (fp32), split-K atomics, one bh
__global__ __launch_bounds__(256) void k_av(const float* __restrict__ Pb, const float* __restrict__ Vb,
                                            float* __restrict__ avb){
  const int mt = blockIdx.y, kc = blockIdx.x;
  const int m0 = mt * 64;
  __shared__ float As[16][64];
  __shared__ float Bs[16][64];
  const int tid = threadIdx.x, ty = tid >> 4, tx = tid & 15;
  const int lm = tid >> 2, lk = (tid & 3) << 2;
  const int lk2 = tid >> 4, ln = (tid & 15) << 2;
  float acc[4][4] = {};
  const int kbeg = kc * 512;
  for (int k0 = kbeg; k0 < kbeg + 512; k0 += 16){
    float4 a4 = *(const float4*)(Pb + (size_t)(m0 + lm) * NTOK + k0 + lk);
    As[lk+0][lm] = a4.x; As[lk+1][lm] = a4.y; As[lk+2][lm] = a4.z; As[lk+3][lm] = a4.w;
    float4 b4 = *(const float4*)(Vb + (size_t)(k0 + lk2) * DH + ln);
    *(float4*)&Bs[lk2][ln] = b4;
    __syncthreads();
#pragma unroll
    for (int kk = 0; kk < 16; kk++){
      float a[4], bv[4];
#pragma unroll
      for (int r = 0; r < 4; r++) a[r] = As[kk][ty*4 + r];
#pragma unroll
      for (int c = 0; c < 4; c++) bv[c] = Bs[kk][tx*4 + c];
#pragma unroll
      for (int r = 0; r < 4; r++)
#pragma unroll
        for (int c = 0; c < 4; c++) acc[r][c] += a[r] * bv[c];
    }
    __syncthreads();
  }
#pragma unroll
  for (int r = 0; r < 4; r++)
#pragma unroll
    for (int c = 0; c < 4; c++)
      atomicAdd(&avb[(size_t)(m0 + ty*4 + r) * DH + tx*4 + c], acc[r][c]);
}

// ---------------- w2 = z_final @ av (fp32, M=256,N=64,K=256), batched
__global__ __launch_bounds__(256) void k_w2(const float* __restrict__ Z, const float* __restrict__ AV,
                                            float* __restrict__ W2){
  const int bh = blockIdx.y, mt = blockIdx.x;
  const float* Zb = Z + (size_t)bh * 65536;
  const float* Vb = AV + (size_t)bh * MLM * DH;
  float* Wb = W2 + (size_t)bh * MLM * DH;
  const int m0 = mt * 64;
  __shared__ float As[16][64];
  __shared__ float Bs[16][64];
  const int tid = threadIdx.x, ty = tid >> 4, tx = tid & 15;
  const int lm = tid >> 2, lk = (tid & 3) << 2;
  const int lk2 = tid >> 4, ln = (tid & 15) << 2;
  float acc[4][4] = {};
  for (int k0 = 0; k0 < 256; k0 += 16){
    float4 a4 = *(const float4*)(Zb + (size_t)(m0 + lm) * 256 + k0 + lk);
    As[lk+0][lm] = a4.x; As[lk+1][lm] = a4.y; As[lk+2][lm] = a4.z; As[lk+3][lm] = a4.w;
    float4 b4 = *(const float4*)(Vb + (size_t)(k0 + lk2) * DH + ln);
    *(float4*)&Bs[lk2][ln] = b4;
    __syncthreads();
#pragma unroll
    for (int kk = 0; kk < 16; kk++){
      float a[4], bv[4];
#pragma unroll
      for (int r = 0; r < 4; r++) a[r] = As[kk][ty*4 + r];
#pragma unroll
      for (int c = 0; c < 4; c++) bv[c] = Bs[kk][tx*4 + c];
#pragma unroll
      for (int r = 0; r < 4; r++)
#pragma unroll
        for (int c = 0; c < 4; c++) acc[r][c] += a[r] * bv[c];
    }
    __syncthreads();
  }
#pragma unroll
  for (int r = 0; r < 4; r++)
#pragma unroll
    for (int c = 0; c < 4; c++)
      Wb[(size_t)(m0 + ty*4 + r) * DH + tx*4 + c] = acc[r][c];
}

// ---------------- sim1 slice = q @ kl^T (fp32) [8192 x 256], one bh
__global__ __launch_bounds__(256) void k_sim1g(const float* __restrict__ Aq,
                                               const float* __restrict__ Bkl,
                                               float* __restrict__ C){
  const int n0 = blockIdx.x * 64;   // over 256
  const int m0 = blockIdx.y * 64;   // over 8192
  __shared__ float As[16][64];
  __shared__ float Bs[16][64];
  const int tid = threadIdx.x, ty = tid >> 4, tx = tid & 15;
  const int lm = tid >> 2, lk = (tid & 3) << 2;
  float acc[4][4] = {};
  for (int k0 = 0; k0 < 64; k0 += 16){
    float4 a4 = *(const float4*)(Aq + (size_t)(m0 + lm) * DH + k0 + lk);
    As[lk+0][lm] = a4.x; As[lk+1][lm] = a4.y; As[lk+2][lm] = a4.z; As[lk+3][lm] = a4.w;
    float4 b4 = *(const float4*)(Bkl + (size_t)(n0 + lm) * DH + k0 + lk);
    Bs[lk+0][lm] = b4.x; Bs[lk+1][lm] = b4.y; Bs[lk+2][lm] = b4.z; Bs[lk+3][lm] = b4.w;
    __syncthreads();
#pragma unroll
    for (int kk = 0; kk < 16; kk++){
      float a[4], bv[4];
#pragma unroll
      for (int r = 0; r < 4; r++) a[r] = As[kk][ty*4 + r];
#pragma unroll
      for (int c = 0; c < 4; c++) bv[c] = Bs[kk][tx*4 + c];
#pragma unroll
      for (int r = 0; r < 4; r++)
#pragma unroll
        for (int c = 0; c < 4; c++) acc[r][c] += a[r] * bv[c];
    }
    __syncthreads();
  }
#pragma unroll
  for (int r = 0; r < 4; r++)
#pragma unroll
    for (int c = 0; c < 4; c++)
      C[(size_t)(m0 + ty*4 + r) * MLM + n0 + tx*4 + c] = acc[r][c];
}

// ---------------- epilogue per token: softmax(sim1 row) @ w2 + conv(v) -> oh f32 (in place over q)
__global__ __launch_bounds__(256) void k_ep(const float* __restrict__ sim, const float* __restrict__ w2b,
                                            const float* __restrict__ vfb,
                                            const float* __restrict__ wconv,
                                            float* __restrict__ ohb, int h){
  const int i = blockIdx.x;           // token [0,8192)
  const int t = threadIdx.x;
  __shared__ float P[256];
  __shared__ float red[256];
  __shared__ float r2[4][64];
  float sv = sim[(size_t)i * 256 + t];
  red[t] = sv; __syncthreads();
  for (int o = 128; o > 0; o >>= 1){ if (t < o) red[t] = fmaxf(red[t], red[t+o]); __syncthreads(); }
  float mx = red[0]; __syncthreads();
  float e = expf(sv - mx);
  red[t] = e; __syncthreads();
  for (int o = 128; o > 0; o >>= 1){ if (t < o) red[t] += red[t+o]; __syncthreads(); }
  P[t] = e / red[0];
  __syncthreads();
  const int d = t & 63, qd = t >> 6;
  float a = 0.f;
  for (int j = qd*64; j < qd*64 + 64; j++) a += P[j] * w2b[(size_t)j * DH + d];
  r2[qd][d] = a; __syncthreads();
  if (t < 64){
    float o4 = r2[0][t] + r2[1][t] + r2[2][t] + r2[3][t];
    for (int tt = 0; tt < 33; tt++){
      const int idx = i + tt - 16;
      if (idx >= 0 && idx < NTOK)
        o4 += wconv[h*33 + tt] * vfb[(size_t)idx * DH + t];
    }
    ohb[(size_t)i * DH + t] = o4;
  }
}

// ---------------- final: out = x + b_out + OH(gathered) @ w_out (fp32 out)
__global__ __launch_bounds__(256) void k_final(const float* __restrict__ oh,
                                               const float* __restrict__ wout,
                                               const float* __restrict__ xin,
                                               const float* __restrict__ bout,
                                               float* __restrict__ outp){
  const int n0 = blockIdx.x * 64;   // over 512
  const int m0 = blockIdx.y * 64;   // over 16384
  __shared__ float As[16][64];
  __shared__ float Bs[16][64];
  const int tid = threadIdx.x, ty = tid >> 4, tx = tid & 15;
  const int lm = tid >> 2, lk = (tid & 3) << 2;
  const int lk2 = tid >> 4, ln = (tid & 15) << 2;
  const int row_l = m0 + lm;
  const int bb_l = row_l >> 13, i_l = row_l & 8191;
  float acc[4][4] = {};
  for (int k0 = 0; k0 < 512; k0 += 16){
    const int kidx = k0 + lk;
    const int hh = kidx >> 6, dd = kidx & 63;
    float4 a4 = *(const float4*)(oh + (((size_t)(bb_l * NHEAD + hh)) * NTOK + i_l) * DH + dd);
    As[lk+0][lm] = a4.x; As[lk+1][lm] = a4.y; As[lk+2][lm] = a4.z; As[lk+3][lm] = a4.w;
    float4 b4 = *(const float4*)(wout + (size_t)(k0 + lk2) * 512 + n0 + ln);
    Bs[lk2][ln+0] = b4.x; Bs[lk2][ln+1] = b4.y; Bs[lk2][ln+2] = b4.z; Bs[lk2][ln+3] = b4.w;
    __syncthreads();
#pragma unroll
    for (int kk = 0; kk < 16; kk++){
      float a[4], bv[4];
#pragma unroll
      for (int r = 0; r < 4; r++) a[r] = As[kk][ty*4 + r];
#pragma unroll
      for (int c = 0; c < 4; c++) bv[c] = Bs[kk][tx*4 + c];
#pragma unroll
      for (int r = 0; r < 4; r++)
#pragma unroll
        for (int c = 0; c < 4; c++) acc[r][c] += a[r] * bv[c];
    }
    __syncthreads();
  }
#pragma unroll
  for (int r = 0; r < 4; r++){
    const int row = m0 + ty*4 + r;
#pragma unroll
    for (int c = 0; c < 4; c++){
      const int col = n0 + tx*4 + c;
      outp[(size_t)row * 512 + col] = acc[r][c] + bout[col] + xin[(size_t)row * 512 + col];
    }
  }
}

extern "C" void kernel_launch(void* const* d_in, const int* in_sizes, int n_in,
                              void* d_out, int out_size, void* d_ws, size_t ws_size,
                              hipStream_t stream){
  (void)in_sizes; (void)n_in; (void)out_size; (void)ws_size;
  const float* x     = (const float*)d_in[0];
  const float* wqkv  = (const float*)d_in[1];
  const float* wout  = (const float*)d_in[2];
  const float* bout  = (const float*)d_in[3];
  const float* wconv = (const float*)d_in[4];
  float* outp = (float*)d_out;

  char* base = (char*)d_ws;
  auto alloc = [&](size_t bytes)->char*{
    char* p = base; base += (bytes + 255) & ~(size_t)255; return p;
  };
  const size_t QS = (size_t)BH * NTOK * DH;   // 8388608
  const size_t LS = (size_t)BH * MLM * DH;    // 262144
  const size_t MM = (size_t)BH * MLM * MLM;   // 1048576

  float* qf   = (float*)alloc(QS * 4);   // q (scaled); oh written in place later
  float* kf   = (float*)alloc(QS * 4);
  float* vf   = (float*)alloc(QS * 4);
  float* qlf  = (float*)alloc(LS * 4);
  float* klf  = (float*)alloc(LS * 4);
  float* a2   = (float*)alloc(MM * 4);
  float* zb   = (float*)alloc(MM * 4);
  float* z2   = (float*)alloc(MM * 4);
  float* xz   = (float*)alloc(MM * 4);
  float* t2   = (float*)alloc(MM * 4);
  float* t4   = (float*)alloc(MM * 4);
  float* part = (float*)alloc(64 * 4);
  float* av   = (float*)alloc(LS * 4);
  float* w2   = (float*)alloc(LS * 4);
  float* sim  = (float*)alloc((size_t)MLM * NTOK * 4);   // 8 MB reusable slice
  // total ~138.5 MB

  // 1. QKV projection
  k_qkv<<<dim3(24, 256), 256, 0, stream>>>(x, wqkv, qf, kf, vf);
  // 2. landmarks (fp32)
  k_land<<<BH * MLM, 64, 0, stream>>>(qf, qlf);
  k_land<<<BH * MLM, 64, 0, stream>>>(kf, klf);
  // 3. sim2 + softmax -> attn2
  k_sim2<<<dim3(4, 4, BH), 256, 0, stream>>>(qlf, klf, xz);
  k_softmax256<<<BH * MLM, 256, 0, stream>>>(xz, a2);
  // 4. pinv init
  k_colrow<<<BH, 256, 0, stream>>>(a2, part);
  k_z0<<<BH * MLM, 256, 0, stream>>>(a2, part, zb);
  // 5. 6 Newton-Schulz iterations (fp32)
  float* zc = zb; float* zn = z2;
  for (int it = 0; it < 6; ++it){
    k_gemm256<<<dim3(16, BH), 256, 0, stream>>>(a2, zc, a2, xz, 0.f, -1.f);   // xz = a2@z
    k_gemm256<<<dim3(16, BH), 256, 0, stream>>>(xz, xz, xz, t2, 7.f, 1.f);    // t2 = 7xz - xz@xz
    k_gemm256<<<dim3(16, BH), 256, 0, stream>>>(xz, t2, xz, t4, 15.f, 1.f);   // t4 = 15xz - xz@t2
    k_gemm256<<<dim3(16, BH), 256, 0, stream>>>(zc, t4, zc, zn, 13.f, 0.25f); // z' = .25(13z - z@t4)
    float* tmp = zc; zc = zn; zn = tmp;
  }
  // 6. per-bh: sim3 -> softmax over n -> av (split-K atomics)
  k_zero<<<((int)LS + 255) / 256, 256, 0, stream>>>(av, (int)LS);
  for (int bh = 0; bh < BH; ++bh){
    k_sim3<<<dim3(128, 4), 256, 0, stream>>>(qlf + (size_t)bh * MLM * DH,
                                             kf + (size_t)bh * NTOK * DH, sim);
    k_softmax_n<<<MLM, 256, 0, stream>>>(sim);
    k_av<<<dim3(16, 4), 256, 0, stream>>>(sim, vf + (size_t)bh * NTOK * DH,
                                          av + (size_t)bh * MLM * DH);
  }
  // 7. w2 = z_final @ av
  k_w2<<<dim3(4, BH), 256, 0, stream>>>(zc, av, w2);
  // 8. per-bh: sim1 -> fused softmax/@w2/conv epilogue; oh overwrites q slice
  for (int bh = 0; bh < BH; ++bh){
    float* qslice = qf + (size_t)bh * NTOK * DH;
    k_sim1g<<<dim3(4, 128), 256, 0, stream>>>(qslice, klf + (size_t)bh * MLM * DH, sim);
    k_ep<<<NTOK, 256, 0, stream>>>(sim, w2 + (size_t)bh * MLM * DH,
                                   vf + (size_t)bh * NTOK * DH, wconv, qslice, bh & 7);
  }
  // 9. output projection + residual
  k_final<<<dim3(8, 256), 256, 0, stream>>>(qf, wout, x, bout, outp);
}

// Round 6
// 1769.406 us; speedup vs baseline: 1.7252x; 1.7252x over previous
//
#include <hip/hip_runtime.h>
#include <hip/hip_bf16.h>

#define BH 16
#define NTOK 8192
#define NHEAD 8
#define DH 64
#define MLM 256
#define QSCALE 0.125f

// ---------------- zero fill
__global__ __launch_bounds__(256) void k_zero(float* __restrict__ p, int n){
  int i = blockIdx.x * 256 + threadIdx.x;
  if (i < n) p[i] = 0.f;
}

// ---------------- QKV projection: x[16384,512]f32 @ wqkv[512,1536]f32 -> q,k,v f32 [bh][n][dh]
__global__ __launch_bounds__(256) void k_qkv(const float* __restrict__ x,
                                             const float* __restrict__ wqkv,
                                             float* __restrict__ q,
                                             float* __restrict__ k,
                                             float* __restrict__ v){
  const int n0 = blockIdx.x * 64;   // over 1536
  const int m0 = blockIdx.y * 64;   // over 16384
  __shared__ float As[16][64];
  __shared__ float Bs[16][64];
  const int tid = threadIdx.x, ty = tid >> 4, tx = tid & 15;
  const int lm = tid >> 2, lk = (tid & 3) << 2;
  const int lk2 = tid >> 4, ln = (tid & 15) << 2;
  float acc[4][4] = {};
  for (int k0 = 0; k0 < 512; k0 += 16){
    float4 a4 = *(const float4*)(x + (size_t)(m0 + lm) * 512 + k0 + lk);
    As[lk+0][lm] = a4.x; As[lk+1][lm] = a4.y; As[lk+2][lm] = a4.z; As[lk+3][lm] = a4.w;
    float4 b4 = *(const float4*)(wqkv + (size_t)(k0 + lk2) * 1536 + n0 + ln);
    Bs[lk2][ln+0] = b4.x; Bs[lk2][ln+1] = b4.y; Bs[lk2][ln+2] = b4.z; Bs[lk2][ln+3] = b4.w;
    __syncthreads();
#pragma unroll
    for (int kk = 0; kk < 16; kk++){
      float a[4], bv[4];
#pragma unroll
      for (int r = 0; r < 4; r++) a[r] = As[kk][ty*4 + r];
#pragma unroll
      for (int c = 0; c < 4; c++) bv[c] = Bs[kk][tx*4 + c];
#pragma unroll
      for (int r = 0; r < 4; r++)
#pragma unroll
        for (int c = 0; c < 4; c++) acc[r][c] += a[r] * bv[c];
    }
    __syncthreads();
  }
#pragma unroll
  for (int r = 0; r < 4; r++){
    const int row = m0 + ty*4 + r;
    const int bb = row >> 13, i = row & 8191;
#pragma unroll
    for (int c = 0; c < 4; c++){
      const int col = n0 + tx*4 + c;
      const int which = col >> 9;
      const int cc = col & 511;
      const int h = cc >> 6, d = cc & 63;
      const size_t off = (((size_t)(bb * NHEAD + h)) * NTOK + i) * DH + d;
      float val = acc[r][c];
      if (which == 0)      q[off] = val * QSCALE;
      else if (which == 1) k[off] = val;
      else                 v[off] = val;
    }
  }
}

// ---------------- landmark means for q and k in one launch (grid.y selects)
__global__ __launch_bounds__(64) void k_land2(const float* __restrict__ qf, const float* __restrict__ kf,
                                              float* __restrict__ qlf, float* __restrict__ klf){
  const float* src = blockIdx.y ? kf : qf;
  float* dst = blockIdx.y ? klf : qlf;
  const int bh = blockIdx.x >> 8;
  const int j  = blockIdx.x & 255;
  const int d  = threadIdx.x;
  const float* p = src + ((size_t)bh * NTOK + (size_t)j * 32) * DH + d;
  float s = 0.f;
#pragma unroll
  for (int t = 0; t < 32; t++) s += p[t * DH];
  dst[((size_t)bh * MLM + j) * DH + d] = s * (1.f / 32.f);
}

// ---------------- sim2 = ql @ kl^T (fp32, K=64), batched [bh][256][256]
__global__ __launch_bounds__(256) void k_sim2(const float* __restrict__ qlf,
                                              const float* __restrict__ klf,
                                              float* __restrict__ C){
  const int bh = blockIdx.z;
  const float* Ab = qlf + (size_t)bh * MLM * DH;
  const float* Bb = klf + (size_t)bh * MLM * DH;
  float* Cb = C + (size_t)bh * MLM * MLM;
  const int n0 = blockIdx.x * 64;
  const int m0 = blockIdx.y * 64;
  __shared__ float As[16][64];
  __shared__ float Bs[16][64];
  const int tid = threadIdx.x, ty = tid >> 4, tx = tid & 15;
  const int lm = tid >> 2, lk = (tid & 3) << 2;
  float acc[4][4] = {};
  for (int k0 = 0; k0 < 64; k0 += 16){
    float4 a4 = *(const float4*)(Ab + (size_t)(m0 + lm) * DH + k0 + lk);
    As[lk+0][lm] = a4.x; As[lk+1][lm] = a4.y; As[lk+2][lm] = a4.z; As[lk+3][lm] = a4.w;
    float4 b4 = *(const float4*)(Bb + (size_t)(n0 + lm) * DH + k0 + lk);
    Bs[lk+0][lm] = b4.x; Bs[lk+1][lm] = b4.y; Bs[lk+2][lm] = b4.z; Bs[lk+3][lm] = b4.w;
    __syncthreads();
#pragma unroll
    for (int kk = 0; kk < 16; kk++){
      float a[4], bv[4];
#pragma unroll
      for (int r = 0; r < 4; r++) a[r] = As[kk][ty*4 + r];
#pragma unroll
      for (int c = 0; c < 4; c++) bv[c] = Bs[kk][tx*4 + c];
#pragma unroll
      for (int r = 0; r < 4; r++)
#pragma unroll
        for (int c = 0; c < 4; c++) acc[r][c] += a[r] * bv[c];
    }
    __syncthreads();
  }
#pragma unroll
  for (int r = 0; r < 4; r++)
#pragma unroll
    for (int c = 0; c < 4; c++)
      Cb[(size_t)(m0 + ty*4 + r) * MLM + n0 + tx*4 + c] = acc[r][c];
}

// ---------------- row softmax over 256
__global__ __launch_bounds__(256) void k_softmax256(const float* __restrict__ in, float* __restrict__ outp){
  const int row = blockIdx.x;
  const int t = threadIdx.x;
  float v = in[(size_t)row * 256 + t];
  __shared__ float red[256];
  red[t] = v; __syncthreads();
  for (int o = 128; o > 0; o >>= 1){ if (t < o) red[t] = fmaxf(red[t], red[t+o]); __syncthreads(); }
  float mx = red[0]; __syncthreads();
  float e = expf(v - mx);
  red[t] = e; __syncthreads();
  for (int o = 128; o > 0; o >>= 1){ if (t < o) red[t] += red[t+o]; __syncthreads(); }
  outp[(size_t)row * 256 + t] = e / red[0];
}

// ---------------- per-batch row/col abs-sum maxima partials
__global__ __launch_bounds__(256) void k_colrow(const float* __restrict__ a2, float* __restrict__ part){
  const int bh = blockIdx.x;
  const int t = threadIdx.x;
  const float* p = a2 + (size_t)bh * 65536;
  float rs = 0.f, cs = 0.f;
  for (int j = 0; j < 256; j++) rs += fabsf(p[(size_t)t * 256 + j]);
  for (int i = 0; i < 256; i++) cs += fabsf(p[(size_t)i * 256 + t]);
  __shared__ float r1[256], r2[256];
  r1[t] = rs; r2[t] = cs; __syncthreads();
  for (int o = 128; o > 0; o >>= 1){
    if (t < o){ r1[t] = fmaxf(r1[t], r1[t+o]); r2[t] = fmaxf(r2[t], r2[t+o]); }
    __syncthreads();
  }
  if (t == 0){ part[bh] = r1[0]; part[16 + bh] = r2[0]; }
}

// ---------------- z0 = a2^T * (1/(col*row)), GLOBAL maxima over all bh
__global__ __launch_bounds__(256) void k_z0(const float* __restrict__ a2, const float* __restrict__ part,
                                            float* __restrict__ z){
  const int bh = blockIdx.x >> 8;
  const int i  = blockIdx.x & 255;
  const int j  = threadIdx.x;
  float m1 = 0.f, m2 = 0.f;
#pragma unroll
  for (int t = 0; t < 16; t++){ m1 = fmaxf(m1, part[t]); m2 = fmaxf(m2, part[16 + t]); }
  const float sc = 1.f / (m1 * m2);
  z[((size_t)bh * 256 + i) * 256 + j] = a2[((size_t)bh * 256 + j) * 256 + i] * sc;
}

// ---------------- batched 256^3 GEMM with pinv epilogue: C = s0*(c0*D - A@B)
__global__ __launch_bounds__(256) void k_gemm256(const float* __restrict__ A, const float* __restrict__ Bm,
                                                 const float* __restrict__ D, float* __restrict__ C,
                                                 float c0, float s0){
  const int bh = blockIdx.y;
  const int mt = blockIdx.x >> 2, nt = blockIdx.x & 3;
  const size_t bo = (size_t)bh * 65536;
  const float* Ab = A + bo; const float* Bb = Bm + bo;
  const float* Db = D + bo; float* Cb = C + bo;
  __shared__ float As[16][64];
  __shared__ float Bs[16][64];
  const int tid = threadIdx.x, ty = tid >> 4, tx = tid & 15;
  const int lm = tid >> 2, lk = (tid & 3) << 2;
  const int lk2 = tid >> 4, ln = (tid & 15) << 2;
  const int m0 = mt * 64, n0 = nt * 64;
  float acc[4][4] = {};
  for (int k0 = 0; k0 < 256; k0 += 16){
    float4 a4 = *(const float4*)(Ab + (size_t)(m0 + lm) * 256 + k0 + lk);
    As[lk+0][lm] = a4.x; As[lk+1][lm] = a4.y; As[lk+2][lm] = a4.z; As[lk+3][lm] = a4.w;
    float4 b4 = *(const float4*)(Bb + (size_t)(k0 + lk2) * 256 + n0 + ln);
    *(float4*)&Bs[lk2][ln] = b4;
    __syncthreads();
#pragma unroll
    for (int kk = 0; kk < 16; kk++){
      float a[4], bv[4];
#pragma unroll
      for (int r = 0; r < 4; r++) a[r] = As[kk][ty*4 + r];
#pragma unroll
      for (int c = 0; c < 4; c++) bv[c] = Bs[kk][tx*4 + c];
#pragma unroll
      for (int r = 0; r < 4; r++)
#pragma unroll
        for (int c = 0; c < 4; c++) acc[r][c] += a[r] * bv[c];
    }
    __syncthreads();
  }
#pragma unroll
  for (int r = 0; r < 4; r++)
#pragma unroll
    for (int c = 0; c < 4; c++){
      const size_t idx = (size_t)(m0 + ty*4 + r) * 256 + n0 + tx*4 + c;
      Cb[idx] = s0 * (c0 * Db[idx] - acc[r][c]);
    }
}

// ---------------- flash: partial online-softmax (attn3 @ v) per (kc, mtile, bh), fp32
__global__ __launch_bounds__(256) void k_flash(const float* __restrict__ ql,
                                               const float* __restrict__ kmat,
                                               const float* __restrict__ vmat,
                                               float* __restrict__ pbuf){
  const int kc = blockIdx.x;       // [0,8)
  const int mt = blockIdx.y;       // [0,4)
  const int bh = blockIdx.z;       // [0,16)
  const int m0 = mt * 64;
  const int kbeg = kc * 1024;
  const float* qlb = ql + (size_t)bh * MLM * DH;
  const float* kb  = kmat + (size_t)bh * NTOK * DH;
  const float* vb  = vmat + (size_t)bh * NTOK * DH;
  __shared__ float Qs[64][68];
  __shared__ float Ks[64][68];
  __shared__ float Ps[64][68];
  const int tid = threadIdx.x, ty = tid >> 4, tx = tid & 15;
  // stage Q tile (64 x 64): 1024 float4, 4 per thread
#pragma unroll
  for (int u = 0; u < 4; u++){
    const int f = tid + u * 256, row = f >> 4, c4 = (f & 15) << 2;
    *(float4*)&Qs[row][c4] = *(const float4*)(qlb + (size_t)(m0 + row) * DH + c4);
  }
  float m_run[4], l_run[4], o[4][4];
#pragma unroll
  for (int r = 0; r < 4; r++){
    m_run[r] = -1e30f; l_run[r] = 0.f;
#pragma unroll
    for (int c = 0; c < 4; c++) o[r][c] = 0.f;
  }
  for (int ch = 0; ch < 16; ch++){     // 16 chunks of 64 keys
    const int kr0 = kbeg + ch * 64;
    __syncthreads();                   // prev iter done with Ks/Ps; Qs visible (first iter)
#pragma unroll
    for (int u = 0; u < 4; u++){
      const int f = tid + u * 256, row = f >> 4, c4 = (f & 15) << 2;
      *(float4*)&Ks[row][c4] = *(const float4*)(kb + (size_t)(kr0 + row) * DH + c4);
    }
    __syncthreads();
    float S[4][4] = {};
#pragma unroll
    for (int kk = 0; kk < 64; kk++){
      float a[4], bvv[4];
#pragma unroll
      for (int r = 0; r < 4; r++) a[r] = Qs[ty*4+r][kk];
#pragma unroll
      for (int c = 0; c < 4; c++) bvv[c] = Ks[tx*4+c][kk];
#pragma unroll
      for (int r = 0; r < 4; r++)
#pragma unroll
        for (int c = 0; c < 4; c++) S[r][c] += a[r]*bvv[c];
    }
    float mnew[4], psum[4];
#pragma unroll
    for (int r = 0; r < 4; r++){
      float mx = fmaxf(fmaxf(S[r][0],S[r][1]),fmaxf(S[r][2],S[r][3]));
#pragma unroll
      for (int o2 = 8; o2 >= 1; o2 >>= 1) mx = fmaxf(mx, __shfl_xor(mx, o2));
      mnew[r] = fmaxf(m_run[r], mx);
      float e0=expf(S[r][0]-mnew[r]), e1=expf(S[r][1]-mnew[r]),
            e2=expf(S[r][2]-mnew[r]), e3=expf(S[r][3]-mnew[r]);
      Ps[ty*4+r][tx*4+0]=e0; Ps[ty*4+r][tx*4+1]=e1;
      Ps[ty*4+r][tx*4+2]=e2; Ps[ty*4+r][tx*4+3]=e3;
      float s = e0+e1+e2+e3;
#pragma unroll
      for (int o2 = 8; o2 >= 1; o2 >>= 1) s += __shfl_xor(s, o2);
      psum[r] = s;
    }
    __syncthreads();                   // Ps visible; everyone done reading Ks (as K)
#pragma unroll
    for (int u = 0; u < 4; u++){       // load V chunk into Ks
      const int f = tid + u * 256, row = f >> 4, c4 = (f & 15) << 2;
      *(float4*)&Ks[row][c4] = *(const float4*)(vb + (size_t)(kr0 + row) * DH + c4);
    }
    __syncthreads();
#pragma unroll
    for (int r = 0; r < 4; r++){
      float alpha = expf(m_run[r] - mnew[r]);
      l_run[r] = l_run[r]*alpha + psum[r];
      m_run[r] = mnew[r];
#pragma unroll
      for (int c = 0; c < 4; c++) o[r][c] *= alpha;
    }
#pragma unroll
    for (int kk = 0; kk < 64; kk++){
      float p[4], vv[4];
#pragma unroll
      for (int r = 0; r < 4; r++) p[r] = Ps[ty*4+r][kk];
#pragma unroll
      for (int c = 0; c < 4; c++) vv[c] = Ks[kk][tx*4+c];
#pragma unroll
      for (int r = 0; r < 4; r++)
#pragma unroll
        for (int c = 0; c < 4; c++) o[r][c] += p[r]*vv[c];
    }
  }
  float* pb = pbuf + (((size_t)bh * 8 + kc) * 256) * 68;
#pragma unroll
  for (int r = 0; r < 4; r++){
    float* rowp = pb + (size_t)(m0 + ty*4 + r) * 68;
#pragma unroll
    for (int c = 0; c < 4; c++) rowp[tx*4+c] = o[r][c];
    if (tx == 0){ rowp[64] = m_run[r]; rowp[65] = l_run[r]; }
  }
}

// ---------------- combine flash partials -> av fp32 [bh][256][64]
__global__ __launch_bounds__(256) void k_comb(const float* __restrict__ pbuf, float* __restrict__ av){
  const int wv = threadIdx.x >> 6, lane = threadIdx.x & 63;
  const int id = blockIdx.x * 4 + wv;   // [0, 4096)
  const int bh = id >> 8, row = id & 255;
  const float* base = pbuf + ((size_t)bh * 8 * 256 + row) * 68;
  float M = -1e30f;
#pragma unroll
  for (int k = 0; k < 8; k++) M = fmaxf(M, base[(size_t)k * 256 * 68 + 64]);
  float L = 0.f, o = 0.f;
#pragma unroll
  for (int k = 0; k < 8; k++){
    const float* p = base + (size_t)k * 256 * 68;
    float w = expf(p[64] - M);
    L += p[65] * w;
    o += p[lane] * w;
  }
  av[((size_t)bh * MLM + row) * DH + lane] = o / L;
}

// ---------------- w2 = z_final @ av (fp32, M=256,N=64,K=256), batched
__global__ __launch_bounds__(256) void k_w2(const float* __restrict__ Z, const float* __restrict__ AV,
                                            float* __restrict__ W2){
  const int bh = blockIdx.y, mt = blockIdx.x;
  const float* Zb = Z + (size_t)bh * 65536;
  const float* Vb = AV + (size_t)bh * MLM * DH;
  float* Wb = W2 + (size_t)bh * MLM * DH;
  const int m0 = mt * 64;
  __shared__ float As[16][64];
  __shared__ float Bs[16][64];
  const int tid = threadIdx.x, ty = tid >> 4, tx = tid & 15;
  const int lm = tid >> 2, lk = (tid & 3) << 2;
  const int lk2 = tid >> 4, ln = (tid & 15) << 2;
  float acc[4][4] = {};
  for (int k0 = 0; k0 < 256; k0 += 16){
    float4 a4 = *(const float4*)(Zb + (size_t)(m0 + lm) * 256 + k0 + lk);
    As[lk+0][lm] = a4.x; As[lk+1][lm] = a4.y; As[lk+2][lm] = a4.z; As[lk+3][lm] = a4.w;
    float4 b4 = *(const float4*)(Vb + (size_t)(k0 + lk2) * DH + ln);
    *(float4*)&Bs[lk2][ln] = b4;
    __syncthreads();
#pragma unroll
    for (int kk = 0; kk < 16; kk++){
      float a[4], bv[4];
#pragma unroll
      for (int r = 0; r < 4; r++) a[r] = As[kk][ty*4 + r];
#pragma unroll
      for (int c = 0; c < 4; c++) bv[c] = Bs[kk][tx*4 + c];
#pragma unroll
      for (int r = 0; r < 4; r++)
#pragma unroll
        for (int c = 0; c < 4; c++) acc[r][c] += a[r] * bv[c];
    }
    __syncthreads();
  }
#pragma unroll
  for (int r = 0; r < 4; r++)
#pragma unroll
    for (int c = 0; c < 4; c++)
      Wb[(size_t)(m0 + ty*4 + r) * DH + tx*4 + c] = acc[r][c];
}

// ---------------- fused attn1 path per (32-token tile, bh):
// S = q@kl^T -> softmax -> @w2 -> + conv(v) -> write oh fp32 IN PLACE over q
__global__ __launch_bounds__(256) void k_attn1(float* __restrict__ qoh,
                                               const float* __restrict__ klf,
                                               const float* __restrict__ vf,
                                               const float* __restrict__ w2,
                                               const float* __restrict__ wconv){
  const int it = blockIdx.x;        // [0,256) tile of 32 tokens
  const int bh = blockIdx.y;        // [0,16)
  const int h  = bh & 7;
  const int i0 = it * 32;
  float* qb = qoh + (size_t)bh * NTOK * DH;
  const float* klb = klf + (size_t)bh * MLM * DH;
  const float* vb  = vf + (size_t)bh * NTOK * DH;
  const float* w2b = w2 + (size_t)bh * MLM * DH;
  __shared__ float Qs[32][68];      // 8.7 KB
  __shared__ float Ks[64][68];      // 17.4 KB (KL chunks -> w2 chunks -> V tile)
  __shared__ float Sl[32][260];     // 33.3 KB
  __shared__ float red[32][8];
  __shared__ float rowm[32], rowsum[32];
  __shared__ float wcs[33];
  const int tid = threadIdx.x;
  if (tid < 33) wcs[tid] = wconv[h*33 + tid];
  // stage Q: 32x64 = 512 float4, 2 per thread
#pragma unroll
  for (int u = 0; u < 2; u++){
    const int f = tid + u * 256, row = f >> 4, c4 = (f & 15) << 2;
    *(float4*)&Qs[row][c4] = *(const float4*)(qb + (size_t)(i0 + row) * DH + c4);
  }
  // phase 1: S = Q @ kl^T in 4 chunks of 64 landmarks
  const int ty8 = tid >> 5, tx32 = tid & 31;     // 8 x 32 thread grid
  for (int jc = 0; jc < 4; jc++){
    __syncthreads();
#pragma unroll
    for (int u = 0; u < 4; u++){
      const int f = tid + u * 256, row = f >> 4, c4 = (f & 15) << 2;
      *(float4*)&Ks[row][c4] = *(const float4*)(klb + (size_t)(jc*64 + row) * DH + c4);
    }
    __syncthreads();
    float acc[4][2] = {};
#pragma unroll
    for (int kk = 0; kk < 64; kk++){
      float a[4];
#pragma unroll
      for (int r = 0; r < 4; r++) a[r] = Qs[ty8*4 + r][kk];
      const float b0 = Ks[tx32][kk], b1 = Ks[tx32 + 32][kk];
#pragma unroll
      for (int r = 0; r < 4; r++){ acc[r][0] += a[r]*b0; acc[r][1] += a[r]*b1; }
    }
#pragma unroll
    for (int r = 0; r < 4; r++){
      Sl[ty8*4 + r][jc*64 + tx32]      = acc[r][0];
      Sl[ty8*4 + r][jc*64 + tx32 + 32] = acc[r][1];
    }
  }
  __syncthreads();
  // phase 2: softmax rows of Sl (8 threads per row, 32 cols each)
  {
    const int row = tid >> 3, part = tid & 7;
    float mx = -1e30f;
#pragma unroll 8
    for (int j = 0; j < 32; j++) mx = fmaxf(mx, Sl[row][part*32 + j]);
    red[row][part] = mx; __syncthreads();
    if (part == 0){
      float m = red[row][0];
#pragma unroll
      for (int u = 1; u < 8; u++) m = fmaxf(m, red[row][u]);
      rowm[row] = m;
    }
    __syncthreads();
    const float m = rowm[row];
    float s = 0.f;
#pragma unroll 8
    for (int j = 0; j < 32; j++){
      float e = expf(Sl[row][part*32 + j] - m);
      Sl[row][part*32 + j] = e;
      s += e;
    }
    red[row][part] = s; __syncthreads();
    if (part == 0){
      float t = 0.f;
#pragma unroll
      for (int u = 0; u < 8; u++) t += red[row][u];
      rowsum[row] = t;
    }
    __syncthreads();
    const float inv = 1.f / rowsum[row];
#pragma unroll 8
    for (int j = 0; j < 32; j++) Sl[row][part*32 + j] *= inv;
  }
  // phase 3: O = P @ w2  (each thread: 8 rows x 1 col)
  const int d = tid & 63, rg = tid >> 6;   // rg in [0,4), rows rg*8..rg*8+7
  float o8[8] = {};
  for (int jc2 = 0; jc2 < 4; jc2++){
    __syncthreads();
#pragma unroll
    for (int u = 0; u < 4; u++){
      const int f = tid + u * 256, row = f >> 4, c4 = (f & 15) << 2;
      *(float4*)&Ks[row][c4] = *(const float4*)(w2b + (size_t)(jc2*64 + row) * DH + c4);
    }
    __syncthreads();
#pragma unroll
    for (int j = 0; j < 64; j++){
      const float w = Ks[j][d];
#pragma unroll
      for (int rr = 0; rr < 8; rr++) o8[rr] += Sl[rg*8 + rr][jc2*64 + j] * w;
    }
  }
  // phase 4: conv residual; stage V rows [i0-16, i0+47] into Ks (zero-padded)
  __syncthreads();
#pragma unroll
  for (int u = 0; u < 4; u++){
    const int f = tid + u * 256, row = f >> 4, c4 = (f & 15) << 2;
    const int g = i0 - 16 + row;
    float4 vv = make_float4(0.f, 0.f, 0.f, 0.f);
    if (g >= 0 && g < NTOK) vv = *(const float4*)(vb + (size_t)g * DH + c4);
    *(float4*)&Ks[row][c4] = vv;
  }
  __syncthreads();
#pragma unroll 3
  for (int t = 0; t < 33; t++){
    const float w = wcs[t];
#pragma unroll
    for (int rr = 0; rr < 8; rr++) o8[rr] += w * Ks[rg*8 + rr + t][d];
  }
  // phase 5: write in place over q tile
#pragma unroll
  for (int rr = 0; rr < 8; rr++)
    qb[(size_t)(i0 + rg*8 + rr) * DH + d] = o8[rr];
}

// ---------------- final: out = x + b_out + OH(gathered) @ w_out (fp32 out)
__global__ __launch_bounds__(256) void k_final(const float* __restrict__ oh,
                                               const float* __restrict__ wout,
                                               const float* __restrict__ xin,
                                               const float* __restrict__ bout,
                                               float* __restrict__ outp){
  const int n0 = blockIdx.x * 64;   // over 512
  const int m0 = blockIdx.y * 64;   // over 16384
  __shared__ float As[16][64];
  __shared__ float Bs[16][64];
  const int tid = threadIdx.x, ty = tid >> 4, tx = tid & 15;
  const int lm = tid >> 2, lk = (tid & 3) << 2;
  const int lk2 = tid >> 4, ln = (tid & 15) << 2;
  const int row_l = m0 + lm;
  const int bb_l = row_l >> 13, i_l = row_l & 8191;
  float acc[4][4] = {};
  for (int k0 = 0; k0 < 512; k0 += 16){
    const int kidx = k0 + lk;
    const int hh = kidx >> 6, dd = kidx & 63;
    float4 a4 = *(const float4*)(oh + (((size_t)(bb_l * NHEAD + hh)) * NTOK + i_l) * DH + dd);
    As[lk+0][lm] = a4.x; As[lk+1][lm] = a4.y; As[lk+2][lm] = a4.z; As[lk+3][lm] = a4.w;
    float4 b4 = *(const float4*)(wout + (size_t)(k0 + lk2) * 512 + n0 + ln);
    Bs[lk2][ln+0] = b4.x; Bs[lk2][ln+1] = b4.y; Bs[lk2][ln+2] = b4.z; Bs[lk2][ln+3] = b4.w;
    __syncthreads();
#pragma unroll
    for (int kk = 0; kk < 16; kk++){
      float a[4], bv[4];
#pragma unroll
      for (int r = 0; r < 4; r++) a[r] = As[kk][ty*4 + r];
#pragma unroll
      for (int c = 0; c < 4; c++) bv[c] = Bs[kk][tx*4 + c];
#pragma unroll
      for (int r = 0; r < 4; r++)
#pragma unroll
        for (int c = 0; c < 4; c++) acc[r][c] += a[r] * bv[c];
    }
    __syncthreads();
  }
#pragma unroll
  for (int r = 0; r < 4; r++){
    const int row = m0 + ty*4 + r;
#pragma unroll
    for (int c = 0; c < 4; c++){
      const int col = n0 + tx*4 + c;
      outp[(size_t)row * 512 + col] = acc[r][c] + bout[col] + xin[(size_t)row * 512 + col];
    }
  }
}

extern "C" void kernel_launch(void* const* d_in, const int* in_sizes, int n_in,
                              void* d_out, int out_size, void* d_ws, size_t ws_size,
                              hipStream_t stream){
  (void)in_sizes; (void)n_in; (void)out_size; (void)ws_size;
  const float* x     = (const float*)d_in[0];
  const float* wqkv  = (const float*)d_in[1];
  const float* wout  = (const float*)d_in[2];
  const float* bout  = (const float*)d_in[3];
  const float* wconv = (const float*)d_in[4];
  float* outp = (float*)d_out;

  char* base = (char*)d_ws;
  auto alloc = [&](size_t bytes)->char*{
    char* p = base; base += (bytes + 255) & ~(size_t)255; return p;
  };
  const size_t QS = (size_t)BH * NTOK * DH;   // 8388608
  const size_t LS = (size_t)BH * MLM * DH;    // 262144
  const size_t MM = (size_t)BH * MLM * MLM;   // 1048576

  float* qf   = (float*)alloc(QS * 4);   // q (scaled); oh written in place later
  float* kf   = (float*)alloc(QS * 4);
  float* vf   = (float*)alloc(QS * 4);
  float* qlf  = (float*)alloc(LS * 4);
  float* klf  = (float*)alloc(LS * 4);
  float* a2   = (float*)alloc(MM * 4);
  float* zb   = (float*)alloc(MM * 4);
  float* z2   = (float*)alloc(MM * 4);
  float* xz   = (float*)alloc(MM * 4);
  float* t2   = (float*)alloc(MM * 4);
  float* t4   = (float*)alloc(MM * 4);
  float* part = (float*)alloc(64 * 4);
  float* pbuf = (float*)alloc((size_t)BH * 8 * 256 * 68 * 4);  // 8.9 MB
  float* av   = (float*)alloc(LS * 4);
  float* w2   = (float*)alloc(LS * 4);
  // total ~139 MB

  // 1. QKV projection
  k_qkv<<<dim3(24, 256), 256, 0, stream>>>(x, wqkv, qf, kf, vf);
  // 2. landmarks (q and k in one launch)
  k_land2<<<dim3(BH * MLM, 2), 64, 0, stream>>>(qf, kf, qlf, klf);
  // 3. sim2 + softmax -> attn2
  k_sim2<<<dim3(4, 4, BH), 256, 0, stream>>>(qlf, klf, xz);
  k_softmax256<<<BH * MLM, 256, 0, stream>>>(xz, a2);
  // 4. pinv init
  k_colrow<<<BH, 256, 0, stream>>>(a2, part);
  k_z0<<<BH * MLM, 256, 0, stream>>>(a2, part, zb);
  // 5. 6 Newton-Schulz iterations (fp32)
  float* zc = zb; float* zn = z2;
  for (int it = 0; it < 6; ++it){
    k_gemm256<<<dim3(16, BH), 256, 0, stream>>>(a2, zc, a2, xz, 0.f, -1.f);   // xz = a2@z
    k_gemm256<<<dim3(16, BH), 256, 0, stream>>>(xz, xz, xz, t2, 7.f, 1.f);    // t2 = 7xz - xz@xz
    k_gemm256<<<dim3(16, BH), 256, 0, stream>>>(xz, t2, xz, t4, 15.f, 1.f);   // t4 = 15xz - xz@t2
    k_gemm256<<<dim3(16, BH), 256, 0, stream>>>(zc, t4, zc, zn, 13.f, 0.25f); // z' = .25(13z - z@t4)
    float* tmp = zc; zc = zn; zn = tmp;
  }
  // 6. flash attn3@v (deterministic split-K, no atomics) + combine
  k_flash<<<dim3(8, 4, BH), 256, 0, stream>>>(qlf, kf, vf, pbuf);
  k_comb<<<BH * MLM / 4, 256, 0, stream>>>(pbuf, av);
  // 7. w2 = z_final @ av
  k_w2<<<dim3(4, BH), 256, 0, stream>>>(zc, av, w2);
  // 8. fused sim1 softmax + @w2 + conv; oh overwrites q
  k_attn1<<<dim3(256, BH), 256, 0, stream>>>(qf, klf, vf, w2, wconv);
  // 9. output projection + residual
  k_final<<<dim3(8, 256), 256, 0, stream>>>(qf, wout, x, bout, outp);
}

// Round 7
// 1631.340 us; speedup vs baseline: 1.8712x; 1.0846x over previous
//
#include <hip/hip_runtime.h>
#include <hip/hip_bf16.h>

#define BH 16
#define NTOK 8192
#define NHEAD 8
#define DH 64
#define MLM 256
#define QSCALE 0.125f

// ---------------- QKV projection: x[16384,512] @ wqkv[512,1536] -> q,k,v [bh][n][dh]
// 128x64 tile, 8x4 per thread.
__global__ __launch_bounds__(256) void k_qkv(const float* __restrict__ x,
                                             const float* __restrict__ wqkv,
                                             float* __restrict__ q,
                                             float* __restrict__ k,
                                             float* __restrict__ v){
  const int n0 = blockIdx.x * 64;    // over 1536
  const int m0 = blockIdx.y * 128;   // over 16384
  __shared__ float As[16][132];
  __shared__ float Bs[16][68];
  const int tid = threadIdx.x, ty = tid >> 4, tx = tid & 15;
  float acc[8][4] = {};
  for (int k0 = 0; k0 < 512; k0 += 16){
    // stage A: 128 rows x 16 k (512 float4, 2/thread), transposed scatter
#pragma unroll
    for (int u = 0; u < 2; u++){
      const int f = tid + u * 256;
      const int row = f >> 2, kc4 = (f & 3) << 2;
      float4 a4 = *(const float4*)(x + (size_t)(m0 + row) * 512 + k0 + kc4);
      As[kc4+0][row] = a4.x; As[kc4+1][row] = a4.y;
      As[kc4+2][row] = a4.z; As[kc4+3][row] = a4.w;
    }
    // stage B: 16 rows x 64 cols (1 float4/thread)
    {
      const int row = tid >> 4, c4 = (tid & 15) << 2;
      *(float4*)&Bs[row][c4] = *(const float4*)(wqkv + (size_t)(k0 + row) * 1536 + n0 + c4);
    }
    __syncthreads();
#pragma unroll
    for (int kk = 0; kk < 16; kk++){
      float a[8], bv[4];
#pragma unroll
      for (int r = 0; r < 8; r++) a[r] = As[kk][ty*8 + r];
#pragma unroll
      for (int c = 0; c < 4; c++) bv[c] = Bs[kk][tx*4 + c];
#pragma unroll
      for (int r = 0; r < 8; r++)
#pragma unroll
        for (int c = 0; c < 4; c++) acc[r][c] += a[r] * bv[c];
    }
    __syncthreads();
  }
#pragma unroll
  for (int r = 0; r < 8; r++){
    const int row = m0 + ty*8 + r;
    const int bb = row >> 13, i = row & 8191;
#pragma unroll
    for (int c = 0; c < 4; c++){
      const int col = n0 + tx*4 + c;
      const int which = col >> 9;
      const int cc = col & 511;
      const int h = cc >> 6, d = cc & 63;
      const size_t off = (((size_t)(bb * NHEAD + h)) * NTOK + i) * DH + d;
      float val = acc[r][c];
      if (which == 0)      q[off] = val * QSCALE;
      else if (which == 1) k[off] = val;
      else                 v[off] = val;
    }
  }
}

// ---------------- landmark means for q and k in one launch (grid.y selects)
__global__ __launch_bounds__(64) void k_land2(const float* __restrict__ qf, const float* __restrict__ kf,
                                              float* __restrict__ qlf, float* __restrict__ klf){
  const float* src = blockIdx.y ? kf : qf;
  float* dst = blockIdx.y ? klf : qlf;
  const int bh = blockIdx.x >> 8;
  const int j  = blockIdx.x & 255;
  const int d  = threadIdx.x;
  const float* p = src + ((size_t)bh * NTOK + (size_t)j * 32) * DH + d;
  float s = 0.f;
#pragma unroll
  for (int t = 0; t < 32; t++) s += p[t * DH];
  dst[((size_t)bh * MLM + j) * DH + d] = s * (1.f / 32.f);
}

// ---------------- sim2 = ql @ kl^T (fp32, K=64), batched [bh][256][256]
__global__ __launch_bounds__(256) void k_sim2(const float* __restrict__ qlf,
                                              const float* __restrict__ klf,
                                              float* __restrict__ C){
  const int bh = blockIdx.z;
  const float* Ab = qlf + (size_t)bh * MLM * DH;
  const float* Bb = klf + (size_t)bh * MLM * DH;
  float* Cb = C + (size_t)bh * MLM * MLM;
  const int n0 = blockIdx.x * 64;
  const int m0 = blockIdx.y * 64;
  __shared__ float As[16][64];
  __shared__ float Bs[16][64];
  const int tid = threadIdx.x, ty = tid >> 4, tx = tid & 15;
  const int lm = tid >> 2, lk = (tid & 3) << 2;
  float acc[4][4] = {};
  for (int k0 = 0; k0 < 64; k0 += 16){
    float4 a4 = *(const float4*)(Ab + (size_t)(m0 + lm) * DH + k0 + lk);
    As[lk+0][lm] = a4.x; As[lk+1][lm] = a4.y; As[lk+2][lm] = a4.z; As[lk+3][lm] = a4.w;
    float4 b4 = *(const float4*)(Bb + (size_t)(n0 + lm) * DH + k0 + lk);
    Bs[lk+0][lm] = b4.x; Bs[lk+1][lm] = b4.y; Bs[lk+2][lm] = b4.z; Bs[lk+3][lm] = b4.w;
    __syncthreads();
#pragma unroll
    for (int kk = 0; kk < 16; kk++){
      float a[4], bv[4];
#pragma unroll
      for (int r = 0; r < 4; r++) a[r] = As[kk][ty*4 + r];
#pragma unroll
      for (int c = 0; c < 4; c++) bv[c] = Bs[kk][tx*4 + c];
#pragma unroll
      for (int r = 0; r < 4; r++)
#pragma unroll
        for (int c = 0; c < 4; c++) acc[r][c] += a[r] * bv[c];
    }
    __syncthreads();
  }
#pragma unroll
  for (int r = 0; r < 4; r++)
#pragma unroll
    for (int c = 0; c < 4; c++)
      Cb[(size_t)(m0 + ty*4 + r) * MLM + n0 + tx*4 + c] = acc[r][c];
}

// ---------------- row softmax over 256
__global__ __launch_bounds__(256) void k_softmax256(const float* __restrict__ in, float* __restrict__ outp){
  const int row = blockIdx.x;
  const int t = threadIdx.x;
  float v = in[(size_t)row * 256 + t];
  __shared__ float red[256];
  red[t] = v; __syncthreads();
  for (int o = 128; o > 0; o >>= 1){ if (t < o) red[t] = fmaxf(red[t], red[t+o]); __syncthreads(); }
  float mx = red[0]; __syncthreads();
  float e = expf(v - mx);
  red[t] = e; __syncthreads();
  for (int o = 128; o > 0; o >>= 1){ if (t < o) red[t] += red[t+o]; __syncthreads(); }
  outp[(size_t)row * 256 + t] = e / red[0];
}

// ---------------- per-batch row/col abs-sum maxima partials
__global__ __launch_bounds__(256) void k_colrow(const float* __restrict__ a2, float* __restrict__ part){
  const int bh = blockIdx.x;
  const int t = threadIdx.x;
  const float* p = a2 + (size_t)bh * 65536;
  float rs = 0.f, cs = 0.f;
  for (int j = 0; j < 256; j++) rs += fabsf(p[(size_t)t * 256 + j]);
  for (int i = 0; i < 256; i++) cs += fabsf(p[(size_t)i * 256 + t]);
  __shared__ float r1[256], r2[256];
  r1[t] = rs; r2[t] = cs; __syncthreads();
  for (int o = 128; o > 0; o >>= 1){
    if (t < o){ r1[t] = fmaxf(r1[t], r1[t+o]); r2[t] = fmaxf(r2[t], r2[t+o]); }
    __syncthreads();
  }
  if (t == 0){ part[bh] = r1[0]; part[16 + bh] = r2[0]; }
}

// ---------------- z0 = a2^T * (1/(col*row)), GLOBAL maxima over all bh
__global__ __launch_bounds__(256) void k_z0(const float* __restrict__ a2, const float* __restrict__ part,
                                            float* __restrict__ z){
  const int bh = blockIdx.x >> 8;
  const int i  = blockIdx.x & 255;
  const int j  = threadIdx.x;
  float m1 = 0.f, m2 = 0.f;
#pragma unroll
  for (int t = 0; t < 16; t++){ m1 = fmaxf(m1, part[t]); m2 = fmaxf(m2, part[16 + t]); }
  const float sc = 1.f / (m1 * m2);
  z[((size_t)bh * 256 + i) * 256 + j] = a2[((size_t)bh * 256 + j) * 256 + i] * sc;
}

// ---------------- batched 256^3 GEMM with pinv epilogue: C = s0*(c0*D - A@B)
__global__ __launch_bounds__(256) void k_gemm256(const float* __restrict__ A, const float* __restrict__ Bm,
                                                 const float* __restrict__ D, float* __restrict__ C,
                                                 float c0, float s0){
  const int bh = blockIdx.y;
  const int mt = blockIdx.x >> 2, nt = blockIdx.x & 3;
  const size_t bo = (size_t)bh * 65536;
  const float* Ab = A + bo; const float* Bb = Bm + bo;
  const float* Db = D + bo; float* Cb = C + bo;
  __shared__ float As[16][64];
  __shared__ float Bs[16][64];
  const int tid = threadIdx.x, ty = tid >> 4, tx = tid & 15;
  const int lm = tid >> 2, lk = (tid & 3) << 2;
  const int lk2 = tid >> 4, ln = (tid & 15) << 2;
  const int m0 = mt * 64, n0 = nt * 64;
  float acc[4][4] = {};
  for (int k0 = 0; k0 < 256; k0 += 16){
    float4 a4 = *(const float4*)(Ab + (size_t)(m0 + lm) * 256 + k0 + lk);
    As[lk+0][lm] = a4.x; As[lk+1][lm] = a4.y; As[lk+2][lm] = a4.z; As[lk+3][lm] = a4.w;
    float4 b4 = *(const float4*)(Bb + (size_t)(k0 + lk2) * 256 + n0 + ln);
    *(float4*)&Bs[lk2][ln] = b4;
    __syncthreads();
#pragma unroll
    for (int kk = 0; kk < 16; kk++){
      float a[4], bv[4];
#pragma unroll
      for (int r = 0; r < 4; r++) a[r] = As[kk][ty*4 + r];
#pragma unroll
      for (int c = 0; c < 4; c++) bv[c] = Bs[kk][tx*4 + c];
#pragma unroll
      for (int r = 0; r < 4; r++)
#pragma unroll
        for (int c = 0; c < 4; c++) acc[r][c] += a[r] * bv[c];
    }
    __syncthreads();
  }
#pragma unroll
  for (int r = 0; r < 4; r++)
#pragma unroll
    for (int c = 0; c < 4; c++){
      const size_t idx = (size_t)(m0 + ty*4 + r) * 256 + n0 + tx*4 + c;
      Cb[idx] = s0 * (c0 * Db[idx] - acc[r][c]);
    }
}

// ---------------- flash: partial online-softmax (attn3 @ v) per (kc, mtile, bh), fp32
__global__ __launch_bounds__(256) void k_flash(const float* __restrict__ ql,
                                               const float* __restrict__ kmat,
                                               const float* __restrict__ vmat,
                                               float* __restrict__ pbuf){
  const int kc = blockIdx.x;       // [0,8)
  const int mt = blockIdx.y;       // [0,4)
  const int bh = blockIdx.z;       // [0,16)
  const int m0 = mt * 64;
  const int kbeg = kc * 1024;
  const float* qlb = ql + (size_t)bh * MLM * DH;
  const float* kb  = kmat + (size_t)bh * NTOK * DH;
  const float* vb  = vmat + (size_t)bh * NTOK * DH;
  __shared__ float Qs[64][68];
  __shared__ float Ks[64][68];
  __shared__ float Ps[64][68];
  const int tid = threadIdx.x, ty = tid >> 4, tx = tid & 15;
#pragma unroll
  for (int u = 0; u < 4; u++){
    const int f = tid + u * 256, row = f >> 4, c4 = (f & 15) << 2;
    *(float4*)&Qs[row][c4] = *(const float4*)(qlb + (size_t)(m0 + row) * DH + c4);
  }
  float m_run[4], l_run[4], o[4][4];
#pragma unroll
  for (int r = 0; r < 4; r++){
    m_run[r] = -1e30f; l_run[r] = 0.f;
#pragma unroll
    for (int c = 0; c < 4; c++) o[r][c] = 0.f;
  }
  for (int ch = 0; ch < 16; ch++){
    const int kr0 = kbeg + ch * 64;
    __syncthreads();
#pragma unroll
    for (int u = 0; u < 4; u++){
      const int f = tid + u * 256, row = f >> 4, c4 = (f & 15) << 2;
      *(float4*)&Ks[row][c4] = *(const float4*)(kb + (size_t)(kr0 + row) * DH + c4);
    }
    __syncthreads();
    float S[4][4] = {};
#pragma unroll
    for (int kk = 0; kk < 64; kk++){
      float a[4], bvv[4];
#pragma unroll
      for (int r = 0; r < 4; r++) a[r] = Qs[ty*4+r][kk];
#pragma unroll
      for (int c = 0; c < 4; c++) bvv[c] = Ks[tx*4+c][kk];
#pragma unroll
      for (int r = 0; r < 4; r++)
#pragma unroll
        for (int c = 0; c < 4; c++) S[r][c] += a[r]*bvv[c];
    }
    float mnew[4], psum[4];
#pragma unroll
    for (int r = 0; r < 4; r++){
      float mx = fmaxf(fmaxf(S[r][0],S[r][1]),fmaxf(S[r][2],S[r][3]));
#pragma unroll
      for (int o2 = 8; o2 >= 1; o2 >>= 1) mx = fmaxf(mx, __shfl_xor(mx, o2));
      mnew[r] = fmaxf(m_run[r], mx);
      float e0=expf(S[r][0]-mnew[r]), e1=expf(S[r][1]-mnew[r]),
            e2=expf(S[r][2]-mnew[r]), e3=expf(S[r][3]-mnew[r]);
      Ps[ty*4+r][tx*4+0]=e0; Ps[ty*4+r][tx*4+1]=e1;
      Ps[ty*4+r][tx*4+2]=e2; Ps[ty*4+r][tx*4+3]=e3;
      float s = e0+e1+e2+e3;
#pragma unroll
      for (int o2 = 8; o2 >= 1; o2 >>= 1) s += __shfl_xor(s, o2);
      psum[r] = s;
    }
    __syncthreads();
#pragma unroll
    for (int u = 0; u < 4; u++){
      const int f = tid + u * 256, row = f >> 4, c4 = (f & 15) << 2;
      *(float4*)&Ks[row][c4] = *(const float4*)(vb + (size_t)(kr0 + row) * DH + c4);
    }
    __syncthreads();
#pragma unroll
    for (int r = 0; r < 4; r++){
      float alpha = expf(m_run[r] - mnew[r]);
      l_run[r] = l_run[r]*alpha + psum[r];
      m_run[r] = mnew[r];
#pragma unroll
      for (int c = 0; c < 4; c++) o[r][c] *= alpha;
    }
#pragma unroll
    for (int kk = 0; kk < 64; kk++){
      float p[4], vv[4];
#pragma unroll
      for (int r = 0; r < 4; r++) p[r] = Ps[ty*4+r][kk];
#pragma unroll
      for (int c = 0; c < 4; c++) vv[c] = Ks[kk][tx*4+c];
#pragma unroll
      for (int r = 0; r < 4; r++)
#pragma unroll
        for (int c = 0; c < 4; c++) o[r][c] += p[r]*vv[c];
    }
  }
  float* pb = pbuf + (((size_t)bh * 8 + kc) * 256) * 68;
#pragma unroll
  for (int r = 0; r < 4; r++){
    float* rowp = pb + (size_t)(m0 + ty*4 + r) * 68;
#pragma unroll
    for (int c = 0; c < 4; c++) rowp[tx*4+c] = o[r][c];
    if (tx == 0){ rowp[64] = m_run[r]; rowp[65] = l_run[r]; }
  }
}

// ---------------- combine flash partials -> av fp32 [bh][256][64]
__global__ __launch_bounds__(256) void k_comb(const float* __restrict__ pbuf, float* __restrict__ av){
  const int wv = threadIdx.x >> 6, lane = threadIdx.x & 63;
  const int id = blockIdx.x * 4 + wv;   // [0, 4096)
  const int bh = id >> 8, row = id & 255;
  const float* base = pbuf + ((size_t)bh * 8 * 256 + row) * 68;
  float M = -1e30f;
#pragma unroll
  for (int k = 0; k < 8; k++) M = fmaxf(M, base[(size_t)k * 256 * 68 + 64]);
  float L = 0.f, o = 0.f;
#pragma unroll
  for (int k = 0; k < 8; k++){
    const float* p = base + (size_t)k * 256 * 68;
    float w = expf(p[64] - M);
    L += p[65] * w;
    o += p[lane] * w;
  }
  av[((size_t)bh * MLM + row) * DH + lane] = o / L;
}

// ---------------- w2 = z_final @ av (fp32, M=256,N=64,K=256), batched
__global__ __launch_bounds__(256) void k_w2(const float* __restrict__ Z, const float* __restrict__ AV,
                                            float* __restrict__ W2){
  const int bh = blockIdx.y, mt = blockIdx.x;
  const float* Zb = Z + (size_t)bh * 65536;
  const float* Vb = AV + (size_t)bh * MLM * DH;
  float* Wb = W2 + (size_t)bh * MLM * DH;
  const int m0 = mt * 64;
  __shared__ float As[16][64];
  __shared__ float Bs[16][64];
  const int tid = threadIdx.x, ty = tid >> 4, tx = tid & 15;
  const int lm = tid >> 2, lk = (tid & 3) << 2;
  const int lk2 = tid >> 4, ln = (tid & 15) << 2;
  float acc[4][4] = {};
  for (int k0 = 0; k0 < 256; k0 += 16){
    float4 a4 = *(const float4*)(Zb + (size_t)(m0 + lm) * 256 + k0 + lk);
    As[lk+0][lm] = a4.x; As[lk+1][lm] = a4.y; As[lk+2][lm] = a4.z; As[lk+3][lm] = a4.w;
    float4 b4 = *(const float4*)(Vb + (size_t)(k0 + lk2) * DH + ln);
    *(float4*)&Bs[lk2][ln] = b4;
    __syncthreads();
#pragma unroll
    for (int kk = 0; kk < 16; kk++){
      float a[4], bv[4];
#pragma unroll
      for (int r = 0; r < 4; r++) a[r] = As[kk][ty*4 + r];
#pragma unroll
      for (int c = 0; c < 4; c++) bv[c] = Bs[kk][tx*4 + c];
#pragma unroll
      for (int r = 0; r < 4; r++)
#pragma unroll
        for (int c = 0; c < 4; c++) acc[r][c] += a[r] * bv[c];
    }
    __syncthreads();
  }
#pragma unroll
  for (int r = 0; r < 4; r++)
#pragma unroll
    for (int c = 0; c < 4; c++)
      Wb[(size_t)(m0 + ty*4 + r) * DH + tx*4 + c] = acc[r][c];
}

// ---------------- fused attn1: flash over 4 landmark chunks + conv, 64-token tiles.
// out1 = softmax(q @ kl^T) @ w2 + conv(v); written IN PLACE over q.
// Dynamic LDS: Qs[64][68] | Ks[64][68] | Ps[64][68]  (52224 B); conv V-tile aliases Qs+Ks.
__global__ __launch_bounds__(256) void k_attn1(float* __restrict__ qoh,
                                               const float* __restrict__ klf,
                                               const float* __restrict__ vf,
                                               const float* __restrict__ w2,
                                               const float* __restrict__ wconv){
  extern __shared__ float smem[];
  float (*Qs)[68] = (float (*)[68])smem;
  float (*Ks)[68] = (float (*)[68])(smem + 64*68);
  float (*Ps)[68] = (float (*)[68])(smem + 2*64*68);
  float (*Vs)[68] = (float (*)[68])smem;          // 96x68 alias over Qs+Ks
  __shared__ float wcs[33];
  const int it = blockIdx.x;        // [0,128) tile of 64 tokens
  const int bh = blockIdx.y;        // [0,16)
  const int h  = bh & 7;
  const int i0 = it * 64;
  float* qb = qoh + (size_t)bh * NTOK * DH;
  const float* klb = klf + (size_t)bh * MLM * DH;
  const float* vb  = vf + (size_t)bh * NTOK * DH;
  const float* w2b = w2 + (size_t)bh * MLM * DH;
  const int tid = threadIdx.x, ty = tid >> 4, tx = tid & 15;
  if (tid < 33) wcs[tid] = wconv[h*33 + tid];
#pragma unroll
  for (int u = 0; u < 4; u++){
    const int f = tid + u * 256, row = f >> 4, c4 = (f & 15) << 2;
    *(float4*)&Qs[row][c4] = *(const float4*)(qb + (size_t)(i0 + row) * DH + c4);
  }
  float m_run[4], l_run[4], o[4][4];
#pragma unroll
  for (int r = 0; r < 4; r++){
    m_run[r] = -1e30f; l_run[r] = 0.f;
#pragma unroll
    for (int c = 0; c < 4; c++) o[r][c] = 0.f;
  }
  for (int jc = 0; jc < 4; jc++){
    const int j0 = jc * 64;
    __syncthreads();
#pragma unroll
    for (int u = 0; u < 4; u++){
      const int f = tid + u * 256, row = f >> 4, c4 = (f & 15) << 2;
      *(float4*)&Ks[row][c4] = *(const float4*)(klb + (size_t)(j0 + row) * DH + c4);
    }
    __syncthreads();
    float S[4][4] = {};
#pragma unroll
    for (int kk = 0; kk < 64; kk++){
      float a[4], bvv[4];
#pragma unroll
      for (int r = 0; r < 4; r++) a[r] = Qs[ty*4+r][kk];
#pragma unroll
      for (int c = 0; c < 4; c++) bvv[c] = Ks[tx*4+c][kk];
#pragma unroll
      for (int r = 0; r < 4; r++)
#pragma unroll
        for (int c = 0; c < 4; c++) S[r][c] += a[r]*bvv[c];
    }
    float mnew[4], psum[4];
#pragma unroll
    for (int r = 0; r < 4; r++){
      float mx = fmaxf(fmaxf(S[r][0],S[r][1]),fmaxf(S[r][2],S[r][3]));
#pragma unroll
      for (int o2 = 8; o2 >= 1; o2 >>= 1) mx = fmaxf(mx, __shfl_xor(mx, o2));
      mnew[r] = fmaxf(m_run[r], mx);
      float e0=expf(S[r][0]-mnew[r]), e1=expf(S[r][1]-mnew[r]),
            e2=expf(S[r][2]-mnew[r]), e3=expf(S[r][3]-mnew[r]);
      Ps[ty*4+r][tx*4+0]=e0; Ps[ty*4+r][tx*4+1]=e1;
      Ps[ty*4+r][tx*4+2]=e2; Ps[ty*4+r][tx*4+3]=e3;
      float s = e0+e1+e2+e3;
#pragma unroll
      for (int o2 = 8; o2 >= 1; o2 >>= 1) s += __shfl_xor(s, o2);
      psum[r] = s;
    }
    __syncthreads();   // Ps visible; done reading Ks (kl)
#pragma unroll
    for (int u = 0; u < 4; u++){   // load w2 chunk into Ks
      const int f = tid + u * 256, row = f >> 4, c4 = (f & 15) << 2;
      *(float4*)&Ks[row][c4] = *(const float4*)(w2b + (size_t)(j0 + row) * DH + c4);
    }
    __syncthreads();
#pragma unroll
    for (int r = 0; r < 4; r++){
      float alpha = expf(m_run[r] - mnew[r]);
      l_run[r] = l_run[r]*alpha + psum[r];
      m_run[r] = mnew[r];
#pragma unroll
      for (int c = 0; c < 4; c++) o[r][c] *= alpha;
    }
#pragma unroll
    for (int kk = 0; kk < 64; kk++){
      float p[4], vv[4];
#pragma unroll
      for (int r = 0; r < 4; r++) p[r] = Ps[ty*4+r][kk];
#pragma unroll
      for (int c = 0; c < 4; c++) vv[c] = Ks[kk][tx*4+c];
#pragma unroll
      for (int r = 0; r < 4; r++)
#pragma unroll
        for (int c = 0; c < 4; c++) o[r][c] += p[r]*vv[c];
    }
  }
  // normalize
#pragma unroll
  for (int r = 0; r < 4; r++){
    const float inv = 1.f / l_run[r];
#pragma unroll
    for (int c = 0; c < 4; c++) o[r][c] *= inv;
  }
  // conv: stage v rows [i0-16, i0+79] (96 rows) into Vs (aliases Qs/Ks)
  __syncthreads();
#pragma unroll
  for (int u = 0; u < 6; u++){
    const int f = tid + u * 256, row = f >> 4, c4 = (f & 15) << 2;
    const int g = i0 - 16 + row;
    float4 vv = make_float4(0.f, 0.f, 0.f, 0.f);
    if (g >= 0 && g < NTOK) vv = *(const float4*)(vb + (size_t)g * DH + c4);
    *(float4*)&Vs[row][c4] = vv;
  }
  __syncthreads();
#pragma unroll 3
  for (int t = 0; t < 33; t++){
    const float w = wcs[t];
#pragma unroll
    for (int r = 0; r < 4; r++)
#pragma unroll
      for (int c = 0; c < 4; c++)
        o[r][c] += w * Vs[ty*4 + r + t][tx*4 + c];
  }
  // write in place over q tile
#pragma unroll
  for (int r = 0; r < 4; r++){
    float4 ov; ov.x = o[r][0]; ov.y = o[r][1]; ov.z = o[r][2]; ov.w = o[r][3];
    *(float4*)(qb + (size_t)(i0 + ty*4 + r) * DH + tx*4) = ov;
  }
}

// ---------------- final: out = x + b_out + OH(gathered) @ w_out; 128x64 tile, 8x4/thread
__global__ __launch_bounds__(256) void k_final(const float* __restrict__ oh,
                                               const float* __restrict__ wout,
                                               const float* __restrict__ xin,
                                               const float* __restrict__ bout,
                                               float* __restrict__ outp){
  const int n0 = blockIdx.x * 64;    // over 512
  const int m0 = blockIdx.y * 128;   // over 16384
  __shared__ float As[16][132];
  __shared__ float Bs[16][68];
  const int tid = threadIdx.x, ty = tid >> 4, tx = tid & 15;
  const int bb = m0 >> 13;
  float acc[8][4] = {};
  for (int k0 = 0; k0 < 512; k0 += 16){
#pragma unroll
    for (int u = 0; u < 2; u++){
      const int f = tid + u * 256;
      const int row = f >> 2, kc4 = (f & 3) << 2;
      const int kidx = k0 + kc4;
      const int hh = kidx >> 6, dd = kidx & 63;
      const int i = (m0 + row) & 8191;
      float4 a4 = *(const float4*)(oh + (((size_t)(bb * NHEAD + hh)) * NTOK + i) * DH + dd);
      As[kc4+0][row] = a4.x; As[kc4+1][row] = a4.y;
      As[kc4+2][row] = a4.z; As[kc4+3][row] = a4.w;
    }
    {
      const int row = tid >> 4, c4 = (tid & 15) << 2;
      *(float4*)&Bs[row][c4] = *(const float4*)(wout + (size_t)(k0 + row) * 512 + n0 + c4);
    }
    __syncthreads();
#pragma unroll
    for (int kk = 0; kk < 16; kk++){
      float a[8], bv[4];
#pragma unroll
      for (int r = 0; r < 8; r++) a[r] = As[kk][ty*8 + r];
#pragma unroll
      for (int c = 0; c < 4; c++) bv[c] = Bs[kk][tx*4 + c];
#pragma unroll
      for (int r = 0; r < 8; r++)
#pragma unroll
        for (int c = 0; c < 4; c++) acc[r][c] += a[r] * bv[c];
    }
    __syncthreads();
  }
#pragma unroll
  for (int r = 0; r < 8; r++){
    const int row = m0 + ty*8 + r;
#pragma unroll
    for (int c = 0; c < 4; c++){
      const int col = n0 + tx*4 + c;
      outp[(size_t)row * 512 + col] = acc[r][c] + bout[col] + xin[(size_t)row * 512 + col];
    }
  }
}

extern "C" void kernel_launch(void* const* d_in, const int* in_sizes, int n_in,
                              void* d_out, int out_size, void* d_ws, size_t ws_size,
                              hipStream_t stream){
  (void)in_sizes; (void)n_in; (void)out_size; (void)ws_size;
  const float* x     = (const float*)d_in[0];
  const float* wqkv  = (const float*)d_in[1];
  const float* wout  = (const float*)d_in[2];
  const float* bout  = (const float*)d_in[3];
  const float* wconv = (const float*)d_in[4];
  float* outp = (float*)d_out;

  char* base = (char*)d_ws;
  auto alloc = [&](size_t bytes)->char*{
    char* p = base; base += (bytes + 255) & ~(size_t)255; return p;
  };
  const size_t QS = (size_t)BH * NTOK * DH;   // 8388608
  const size_t LS = (size_t)BH * MLM * DH;    // 262144
  const size_t MM = (size_t)BH * MLM * MLM;   // 1048576

  float* qf   = (float*)alloc(QS * 4);   // q (scaled); oh written in place later
  float* kf   = (float*)alloc(QS * 4);
  float* vf   = (float*)alloc(QS * 4);
  float* qlf  = (float*)alloc(LS * 4);
  float* klf  = (float*)alloc(LS * 4);
  float* a2   = (float*)alloc(MM * 4);
  float* zb   = (float*)alloc(MM * 4);
  float* z2   = (float*)alloc(MM * 4);
  float* xz   = (float*)alloc(MM * 4);
  float* t2   = (float*)alloc(MM * 4);
  float* t4   = (float*)alloc(MM * 4);
  float* part = (float*)alloc(64 * 4);
  float* pbuf = (float*)alloc((size_t)BH * 8 * 256 * 68 * 4);  // 8.9 MB
  float* av   = (float*)alloc(LS * 4);
  float* w2   = (float*)alloc(LS * 4);
  // total ~139 MB

  // 1. QKV projection
  k_qkv<<<dim3(24, 128), 256, 0, stream>>>(x, wqkv, qf, kf, vf);
  // 2. landmarks
  k_land2<<<dim3(BH * MLM, 2), 64, 0, stream>>>(qf, kf, qlf, klf);
  // 3. sim2 + softmax -> attn2
  k_sim2<<<dim3(4, 4, BH), 256, 0, stream>>>(qlf, klf, xz);
  k_softmax256<<<BH * MLM, 256, 0, stream>>>(xz, a2);
  // 4. pinv init
  k_colrow<<<BH, 256, 0, stream>>>(a2, part);
  k_z0<<<BH * MLM, 256, 0, stream>>>(a2, part, zb);
  // 5. 6 Newton-Schulz iterations (fp32)
  float* zc = zb; float* zn = z2;
  for (int it = 0; it < 6; ++it){
    k_gemm256<<<dim3(16, BH), 256, 0, stream>>>(a2, zc, a2, xz, 0.f, -1.f);   // xz = a2@z
    k_gemm256<<<dim3(16, BH), 256, 0, stream>>>(xz, xz, xz, t2, 7.f, 1.f);    // t2 = 7xz - xz@xz
    k_gemm256<<<dim3(16, BH), 256, 0, stream>>>(xz, t2, xz, t4, 15.f, 1.f);   // t4 = 15xz - xz@t2
    k_gemm256<<<dim3(16, BH), 256, 0, stream>>>(zc, t4, zc, zn, 13.f, 0.25f); // z' = .25(13z - z@t4)
    float* tmp = zc; zc = zn; zn = tmp;
  }
  // 6. flash attn3@v + combine
  k_flash<<<dim3(8, 4, BH), 256, 0, stream>>>(qlf, kf, vf, pbuf);
  k_comb<<<BH * MLM / 4, 256, 0, stream>>>(pbuf, av);
  // 7. w2 = z_final @ av
  k_w2<<<dim3(4, BH), 256, 0, stream>>>(zc, av, w2);
  // 8. fused flash attn1 + conv; oh overwrites q
  k_attn1<<<dim3(128, BH), 256, 52224, stream>>>(qf, klf, vf, w2, wconv);
  // 9. output projection + residual
  k_final<<<dim3(8, 128), 256, 0, stream>>>(qf, wout, x, bout, outp);
}

// Round 8
// 1575.198 us; speedup vs baseline: 1.9379x; 1.0356x over previous
//
#include <hip/hip_runtime.h>
#include <hip/hip_bf16.h>

#define BH 16
#define NTOK 8192
#define NHEAD 8
#define DH 64
#define MLM 256
#define QSCALE 0.125f

// ---------------- QKV projection: x[16384,512] @ wqkv[512,1536] -> q,k,v [bh][n][dh]
// 128x64 tile, 8x4 per thread.
__global__ __launch_bounds__(256) void k_qkv(const float* __restrict__ x,
                                             const float* __restrict__ wqkv,
                                             float* __restrict__ q,
                                             float* __restrict__ k,
                                             float* __restrict__ v){
  const int n0 = blockIdx.x * 64;    // over 1536
  const int m0 = blockIdx.y * 128;   // over 16384
  __shared__ float As[16][132];
  __shared__ float Bs[16][68];
  const int tid = threadIdx.x, ty = tid >> 4, tx = tid & 15;
  float acc[8][4] = {};
  for (int k0 = 0; k0 < 512; k0 += 16){
#pragma unroll
    for (int u = 0; u < 2; u++){
      const int f = tid + u * 256;
      const int row = f >> 2, kc4 = (f & 3) << 2;
      float4 a4 = *(const float4*)(x + (size_t)(m0 + row) * 512 + k0 + kc4);
      As[kc4+0][row] = a4.x; As[kc4+1][row] = a4.y;
      As[kc4+2][row] = a4.z; As[kc4+3][row] = a4.w;
    }
    {
      const int row = tid >> 4, c4 = (tid & 15) << 2;
      *(float4*)&Bs[row][c4] = *(const float4*)(wqkv + (size_t)(k0 + row) * 1536 + n0 + c4);
    }
    __syncthreads();
#pragma unroll
    for (int kk = 0; kk < 16; kk++){
      float a[8], bv[4];
#pragma unroll
      for (int r = 0; r < 8; r++) a[r] = As[kk][ty*8 + r];
#pragma unroll
      for (int c = 0; c < 4; c++) bv[c] = Bs[kk][tx*4 + c];
#pragma unroll
      for (int r = 0; r < 8; r++)
#pragma unroll
        for (int c = 0; c < 4; c++) acc[r][c] += a[r] * bv[c];
    }
    __syncthreads();
  }
#pragma unroll
  for (int r = 0; r < 8; r++){
    const int row = m0 + ty*8 + r;
    const int bb = row >> 13, i = row & 8191;
#pragma unroll
    for (int c = 0; c < 4; c++){
      const int col = n0 + tx*4 + c;
      const int which = col >> 9;
      const int cc = col & 511;
      const int h = cc >> 6, d = cc & 63;
      const size_t off = (((size_t)(bb * NHEAD + h)) * NTOK + i) * DH + d;
      float val = acc[r][c];
      if (which == 0)      q[off] = val * QSCALE;
      else if (which == 1) k[off] = val;
      else                 v[off] = val;
    }
  }
}

// ---------------- landmark means for q and k in one launch (grid.y selects)
__global__ __launch_bounds__(64) void k_land2(const float* __restrict__ qf, const float* __restrict__ kf,
                                              float* __restrict__ qlf, float* __restrict__ klf){
  const float* src = blockIdx.y ? kf : qf;
  float* dst = blockIdx.y ? klf : qlf;
  const int bh = blockIdx.x >> 8;
  const int j  = blockIdx.x & 255;
  const int d  = threadIdx.x;
  const float* p = src + ((size_t)bh * NTOK + (size_t)j * 32) * DH + d;
  float s = 0.f;
#pragma unroll
  for (int t = 0; t < 32; t++) s += p[t * DH];
  dst[((size_t)bh * MLM + j) * DH + d] = s * (1.f / 32.f);
}

// ---------------- sim2 = ql @ kl^T (fp32, K=64), batched [bh][256][256]
__global__ __launch_bounds__(256) void k_sim2(const float* __restrict__ qlf,
                                              const float* __restrict__ klf,
                                              float* __restrict__ C){
  const int bh = blockIdx.z;
  const float* Ab = qlf + (size_t)bh * MLM * DH;
  const float* Bb = klf + (size_t)bh * MLM * DH;
  float* Cb = C + (size_t)bh * MLM * MLM;
  const int n0 = blockIdx.x * 64;
  const int m0 = blockIdx.y * 64;
  __shared__ float As[16][64];
  __shared__ float Bs[16][64];
  const int tid = threadIdx.x, ty = tid >> 4, tx = tid & 15;
  const int lm = tid >> 2, lk = (tid & 3) << 2;
  float acc[4][4] = {};
  for (int k0 = 0; k0 < 64; k0 += 16){
    float4 a4 = *(const float4*)(Ab + (size_t)(m0 + lm) * DH + k0 + lk);
    As[lk+0][lm] = a4.x; As[lk+1][lm] = a4.y; As[lk+2][lm] = a4.z; As[lk+3][lm] = a4.w;
    float4 b4 = *(const float4*)(Bb + (size_t)(n0 + lm) * DH + k0 + lk);
    Bs[lk+0][lm] = b4.x; Bs[lk+1][lm] = b4.y; Bs[lk+2][lm] = b4.z; Bs[lk+3][lm] = b4.w;
    __syncthreads();
#pragma unroll
    for (int kk = 0; kk < 16; kk++){
      float a[4], bv[4];
#pragma unroll
      for (int r = 0; r < 4; r++) a[r] = As[kk][ty*4 + r];
#pragma unroll
      for (int c = 0; c < 4; c++) bv[c] = Bs[kk][tx*4 + c];
#pragma unroll
      for (int r = 0; r < 4; r++)
#pragma unroll
        for (int c = 0; c < 4; c++) acc[r][c] += a[r] * bv[c];
    }
    __syncthreads();
  }
#pragma unroll
  for (int r = 0; r < 4; r++)
#pragma unroll
    for (int c = 0; c < 4; c++)
      Cb[(size_t)(m0 + ty*4 + r) * MLM + n0 + tx*4 + c] = acc[r][c];
}

// ---------------- row softmax over 256
__global__ __launch_bounds__(256) void k_softmax256(const float* __restrict__ in, float* __restrict__ outp){
  const int row = blockIdx.x;
  const int t = threadIdx.x;
  float v = in[(size_t)row * 256 + t];
  __shared__ float red[256];
  red[t] = v; __syncthreads();
  for (int o = 128; o > 0; o >>= 1){ if (t < o) red[t] = fmaxf(red[t], red[t+o]); __syncthreads(); }
  float mx = red[0]; __syncthreads();
  float e = expf(v - mx);
  red[t] = e; __syncthreads();
  for (int o = 128; o > 0; o >>= 1){ if (t < o) red[t] += red[t+o]; __syncthreads(); }
  outp[(size_t)row * 256 + t] = e / red[0];
}

// ---------------- per-batch row/col abs-sum maxima partials
__global__ __launch_bounds__(256) void k_colrow(const float* __restrict__ a2, float* __restrict__ part){
  const int bh = blockIdx.x;
  const int t = threadIdx.x;
  const float* p = a2 + (size_t)bh * 65536;
  float rs = 0.f, cs = 0.f;
  for (int j = 0; j < 256; j++) rs += fabsf(p[(size_t)t * 256 + j]);
  for (int i = 0; i < 256; i++) cs += fabsf(p[(size_t)i * 256 + t]);
  __shared__ float r1[256], r2[256];
  r1[t] = rs; r2[t] = cs; __syncthreads();
  for (int o = 128; o > 0; o >>= 1){
    if (t < o){ r1[t] = fmaxf(r1[t], r1[t+o]); r2[t] = fmaxf(r2[t], r2[t+o]); }
    __syncthreads();
  }
  if (t == 0){ part[bh] = r1[0]; part[16 + bh] = r2[0]; }
}

// ---------------- z0 = a2^T * (1/(col*row)), GLOBAL maxima over all bh
__global__ __launch_bounds__(256) void k_z0(const float* __restrict__ a2, const float* __restrict__ part,
                                            float* __restrict__ z){
  const int bh = blockIdx.x >> 8;
  const int i  = blockIdx.x & 255;
  const int j  = threadIdx.x;
  float m1 = 0.f, m2 = 0.f;
#pragma unroll
  for (int t = 0; t < 16; t++){ m1 = fmaxf(m1, part[t]); m2 = fmaxf(m2, part[16 + t]); }
  const float sc = 1.f / (m1 * m2);
  z[((size_t)bh * 256 + i) * 256 + j] = a2[((size_t)bh * 256 + j) * 256 + i] * sc;
}

// ---------------- batched 256^3 GEMM with pinv epilogue: C = s0*(c0*D - A@B)
// 32x64 tiles (512 blocks -> 2 blocks/CU), 4x2 per thread. Same k-order as before.
__global__ __launch_bounds__(256) void k_gemm256(const float* __restrict__ A, const float* __restrict__ Bm,
                                                 const float* __restrict__ D, float* __restrict__ C,
                                                 float c0, float s0){
  const int bh = blockIdx.y;
  const int mt = blockIdx.x >> 2, nt = blockIdx.x & 3;   // mt 0..7, nt 0..3
  const size_t bo = (size_t)bh * 65536;
  const float* Ab = A + bo; const float* Bb = Bm + bo;
  const float* Db = D + bo; float* Cb = C + bo;
  __shared__ float As[16][33];
  __shared__ float Bs[16][66];
  const int tid = threadIdx.x, ty = tid >> 5, tx = tid & 31;  // ty 0..7, tx 0..31
  const int m0 = mt * 32, n0 = nt * 64;
  float acc[4][2] = {};
  for (int k0 = 0; k0 < 256; k0 += 16){
    if (tid < 128){
      const int row = tid >> 2, kc4 = (tid & 3) << 2;
      float4 a4 = *(const float4*)(Ab + (size_t)(m0 + row) * 256 + k0 + kc4);
      As[kc4+0][row] = a4.x; As[kc4+1][row] = a4.y;
      As[kc4+2][row] = a4.z; As[kc4+3][row] = a4.w;
    }
    {
      const int row = tid >> 4, c4 = (tid & 15) << 2;
      *(float4*)&Bs[row][c4] = *(const float4*)(Bb + (size_t)(k0 + row) * 256 + n0 + c4);
    }
    __syncthreads();
#pragma unroll
    for (int kk = 0; kk < 16; kk++){
      float a[4], bv[2];
#pragma unroll
      for (int r = 0; r < 4; r++) a[r] = As[kk][ty*4 + r];
      bv[0] = Bs[kk][tx*2]; bv[1] = Bs[kk][tx*2 + 1];
#pragma unroll
      for (int r = 0; r < 4; r++){
        acc[r][0] += a[r] * bv[0];
        acc[r][1] += a[r] * bv[1];
      }
    }
    __syncthreads();
  }
#pragma unroll
  for (int r = 0; r < 4; r++)
#pragma unroll
    for (int c = 0; c < 2; c++){
      const size_t idx = (size_t)(m0 + ty*4 + r) * 256 + n0 + tx*2 + c;
      Cb[idx] = s0 * (c0 * Db[idx] - acc[r][c]);
    }
}

// ---------------- flash: partial online-softmax (attn3 @ v) per (kc, mtile, bh), fp32
// Conflict-free mapping: thread (ty,tx) owns rows ty*4+r, cols c*16+tx.
__global__ __launch_bounds__(256) void k_flash(const float* __restrict__ ql,
                                               const float* __restrict__ kmat,
                                               const float* __restrict__ vmat,
                                               float* __restrict__ pbuf){
  const int kc = blockIdx.x;       // [0,8)
  const int mt = blockIdx.y;       // [0,4)
  const int bh = blockIdx.z;       // [0,16)
  const int m0 = mt * 64;
  const int kbeg = kc * 1024;
  const float* qlb = ql + (size_t)bh * MLM * DH;
  const float* kb  = kmat + (size_t)bh * NTOK * DH;
  const float* vb  = vmat + (size_t)bh * NTOK * DH;
  __shared__ float Qs[64][68];
  __shared__ float Ks[64][68];
  __shared__ float Ps[64][68];
  const int tid = threadIdx.x, ty = tid >> 4, tx = tid & 15;
#pragma unroll
  for (int u = 0; u < 4; u++){
    const int f = tid + u * 256, row = f >> 4, c4 = (f & 15) << 2;
    *(float4*)&Qs[row][c4] = *(const float4*)(qlb + (size_t)(m0 + row) * DH + c4);
  }
  float m_run[4], l_run[4], o[4][4];
#pragma unroll
  for (int r = 0; r < 4; r++){
    m_run[r] = -1e30f; l_run[r] = 0.f;
#pragma unroll
    for (int c = 0; c < 4; c++) o[r][c] = 0.f;
  }
  for (int ch = 0; ch < 16; ch++){
    const int kr0 = kbeg + ch * 64;
    __syncthreads();
#pragma unroll
    for (int u = 0; u < 4; u++){
      const int f = tid + u * 256, row = f >> 4, c4 = (f & 15) << 2;
      *(float4*)&Ks[row][c4] = *(const float4*)(kb + (size_t)(kr0 + row) * DH + c4);
    }
    __syncthreads();
    float S[4][4] = {};
#pragma unroll
    for (int kk = 0; kk < 64; kk++){
      float a[4], bvv[4];
#pragma unroll
      for (int r = 0; r < 4; r++) a[r] = Qs[ty*4+r][kk];
#pragma unroll
      for (int c = 0; c < 4; c++) bvv[c] = Ks[c*16+tx][kk];
#pragma unroll
      for (int r = 0; r < 4; r++)
#pragma unroll
        for (int c = 0; c < 4; c++) S[r][c] += a[r]*bvv[c];
    }
    float mnew[4], psum[4];
#pragma unroll
    for (int r = 0; r < 4; r++){
      float mx = fmaxf(fmaxf(S[r][0],S[r][1]),fmaxf(S[r][2],S[r][3]));
#pragma unroll
      for (int o2 = 8; o2 >= 1; o2 >>= 1) mx = fmaxf(mx, __shfl_xor(mx, o2));
      mnew[r] = fmaxf(m_run[r], mx);
      float e0=expf(S[r][0]-mnew[r]), e1=expf(S[r][1]-mnew[r]),
            e2=expf(S[r][2]-mnew[r]), e3=expf(S[r][3]-mnew[r]);
      Ps[ty*4+r][0*16+tx]=e0; Ps[ty*4+r][1*16+tx]=e1;
      Ps[ty*4+r][2*16+tx]=e2; Ps[ty*4+r][3*16+tx]=e3;
      float s = e0+e1+e2+e3;
#pragma unroll
      for (int o2 = 8; o2 >= 1; o2 >>= 1) s += __shfl_xor(s, o2);
      psum[r] = s;
    }
    __syncthreads();
#pragma unroll
    for (int u = 0; u < 4; u++){
      const int f = tid + u * 256, row = f >> 4, c4 = (f & 15) << 2;
      *(float4*)&Ks[row][c4] = *(const float4*)(vb + (size_t)(kr0 + row) * DH + c4);
    }
    __syncthreads();
#pragma unroll
    for (int r = 0; r < 4; r++){
      float alpha = expf(m_run[r] - mnew[r]);
      l_run[r] = l_run[r]*alpha + psum[r];
      m_run[r] = mnew[r];
#pragma unroll
      for (int c = 0; c < 4; c++) o[r][c] *= alpha;
    }
#pragma unroll
    for (int kk = 0; kk < 64; kk++){
      float p[4], vv[4];
#pragma unroll
      for (int r = 0; r < 4; r++) p[r] = Ps[ty*4+r][kk];
#pragma unroll
      for (int c = 0; c < 4; c++) vv[c] = Ks[kk][c*16+tx];
#pragma unroll
      for (int r = 0; r < 4; r++)
#pragma unroll
        for (int c = 0; c < 4; c++) o[r][c] += p[r]*vv[c];
    }
  }
  // epilogue: stage o (+m,l) into Ps, then coalesced global write
  __syncthreads();
#pragma unroll
  for (int r = 0; r < 4; r++){
#pragma unroll
    for (int c = 0; c < 4; c++) Ps[ty*4+r][c*16+tx] = o[r][c];
    if (tx == 0){ Ps[ty*4+r][64] = m_run[r]; Ps[ty*4+r][65] = l_run[r]; }
  }
  __syncthreads();
  float* pb = pbuf + (((size_t)bh * 8 + kc) * 256 + m0) * 68;
  for (int f = tid; f < 1088; f += 256){
    const int row = f / 17, g = f % 17;
    *(float4*)(pb + (size_t)row * 68 + g*4) = *(const float4*)&Ps[row][g*4];
  }
}

// ---------------- combine flash partials -> av fp32 [bh][256][64]
__global__ __launch_bounds__(256) void k_comb(const float* __restrict__ pbuf, float* __restrict__ av){
  const int wv = threadIdx.x >> 6, lane = threadIdx.x & 63;
  const int id = blockIdx.x * 4 + wv;   // [0, 4096)
  const int bh = id >> 8, row = id & 255;
  const float* base = pbuf + ((size_t)bh * 8 * 256 + row) * 68;
  float M = -1e30f;
#pragma unroll
  for (int k = 0; k < 8; k++) M = fmaxf(M, base[(size_t)k * 256 * 68 + 64]);
  float L = 0.f, o = 0.f;
#pragma unroll
  for (int k = 0; k < 8; k++){
    const float* p = base + (size_t)k * 256 * 68;
    float w = expf(p[64] - M);
    L += p[65] * w;
    o += p[lane] * w;
  }
  av[((size_t)bh * MLM + row) * DH + lane] = o / L;
}

// ---------------- w2 = z_final @ av (fp32, M=256,N=64,K=256), batched
__global__ __launch_bounds__(256) void k_w2(const float* __restrict__ Z, const float* __restrict__ AV,
                                            float* __restrict__ W2){
  const int bh = blockIdx.y, mt = blockIdx.x;
  const float* Zb = Z + (size_t)bh * 65536;
  const float* Vb = AV + (size_t)bh * MLM * DH;
  float* Wb = W2 + (size_t)bh * MLM * DH;
  const int m0 = mt * 64;
  __shared__ float As[16][64];
  __shared__ float Bs[16][64];
  const int tid = threadIdx.x, ty = tid >> 4, tx = tid & 15;
  const int lm = tid >> 2, lk = (tid & 3) << 2;
  const int lk2 = tid >> 4, ln = (tid & 15) << 2;
  float acc[4][4] = {};
  for (int k0 = 0; k0 < 256; k0 += 16){
    float4 a4 = *(const float4*)(Zb + (size_t)(m0 + lm) * 256 + k0 + lk);
    As[lk+0][lm] = a4.x; As[lk+1][lm] = a4.y; As[lk+2][lm] = a4.z; As[lk+3][lm] = a4.w;
    float4 b4 = *(const float4*)(Vb + (size_t)(k0 + lk2) * DH + ln);
    *(float4*)&Bs[lk2][ln] = b4;
    __syncthreads();
#pragma unroll
    for (int kk = 0; kk < 16; kk++){
      float a[4], bv[4];
#pragma unroll
      for (int r = 0; r < 4; r++) a[r] = As[kk][ty*4 + r];
#pragma unroll
      for (int c = 0; c < 4; c++) bv[c] = Bs[kk][tx*4 + c];
#pragma unroll
      for (int r = 0; r < 4; r++)
#pragma unroll
        for (int c = 0; c < 4; c++) acc[r][c] += a[r] * bv[c];
    }
    __syncthreads();
  }
#pragma unroll
  for (int r = 0; r < 4; r++)
#pragma unroll
    for (int c = 0; c < 4; c++)
      Wb[(size_t)(m0 + ty*4 + r) * DH + tx*4 + c] = acc[r][c];
}

// ---------------- fused attn1: flash over 4 landmark chunks + conv, 64-token tiles.
// Conflict-free mapping (rows ty*4+r, cols c*16+tx); output staged via Ps.
__global__ __launch_bounds__(256) void k_attn1(float* __restrict__ qoh,
                                               const float* __restrict__ klf,
                                               const float* __restrict__ vf,
                                               const float* __restrict__ w2,
                                               const float* __restrict__ wconv){
  extern __shared__ float smem[];
  float (*Qs)[68] = (float (*)[68])smem;
  float (*Ks)[68] = (float (*)[68])(smem + 64*68);
  float (*Ps)[68] = (float (*)[68])(smem + 2*64*68);
  float (*Vs)[68] = (float (*)[68])smem;          // 96x68 alias over Qs+Ks
  __shared__ float wcs[33];
  const int it = blockIdx.x;        // [0,128) tile of 64 tokens
  const int bh = blockIdx.y;        // [0,16)
  const int h  = bh & 7;
  const int i0 = it * 64;
  float* qb = qoh + (size_t)bh * NTOK * DH;
  const float* klb = klf + (size_t)bh * MLM * DH;
  const float* vb  = vf + (size_t)bh * NTOK * DH;
  const float* w2b = w2 + (size_t)bh * MLM * DH;
  const int tid = threadIdx.x, ty = tid >> 4, tx = tid & 15;
  if (tid < 33) wcs[tid] = wconv[h*33 + tid];
#pragma unroll
  for (int u = 0; u < 4; u++){
    const int f = tid + u * 256, row = f >> 4, c4 = (f & 15) << 2;
    *(float4*)&Qs[row][c4] = *(const float4*)(qb + (size_t)(i0 + row) * DH + c4);
  }
  float m_run[4], l_run[4], o[4][4];
#pragma unroll
  for (int r = 0; r < 4; r++){
    m_run[r] = -1e30f; l_run[r] = 0.f;
#pragma unroll
    for (int c = 0; c < 4; c++) o[r][c] = 0.f;
  }
  for (int jc = 0; jc < 4; jc++){
    const int j0 = jc * 64;
    __syncthreads();
#pragma unroll
    for (int u = 0; u < 4; u++){
      const int f = tid + u * 256, row = f >> 4, c4 = (f & 15) << 2;
      *(float4*)&Ks[row][c4] = *(const float4*)(klb + (size_t)(j0 + row) * DH + c4);
    }
    __syncthreads();
    float S[4][4] = {};
#pragma unroll
    for (int kk = 0; kk < 64; kk++){
      float a[4], bvv[4];
#pragma unroll
      for (int r = 0; r < 4; r++) a[r] = Qs[ty*4+r][kk];
#pragma unroll
      for (int c = 0; c < 4; c++) bvv[c] = Ks[c*16+tx][kk];
#pragma unroll
      for (int r = 0; r < 4; r++)
#pragma unroll
        for (int c = 0; c < 4; c++) S[r][c] += a[r]*bvv[c];
    }
    float mnew[4], psum[4];
#pragma unroll
    for (int r = 0; r < 4; r++){
      float mx = fmaxf(fmaxf(S[r][0],S[r][1]),fmaxf(S[r][2],S[r][3]));
#pragma unroll
      for (int o2 = 8; o2 >= 1; o2 >>= 1) mx = fmaxf(mx, __shfl_xor(mx, o2));
      mnew[r] = fmaxf(m_run[r], mx);
      float e0=expf(S[r][0]-mnew[r]), e1=expf(S[r][1]-mnew[r]),
            e2=expf(S[r][2]-mnew[r]), e3=expf(S[r][3]-mnew[r]);
      Ps[ty*4+r][0*16+tx]=e0; Ps[ty*4+r][1*16+tx]=e1;
      Ps[ty*4+r][2*16+tx]=e2; Ps[ty*4+r][3*16+tx]=e3;
      float s = e0+e1+e2+e3;
#pragma unroll
      for (int o2 = 8; o2 >= 1; o2 >>= 1) s += __shfl_xor(s, o2);
      psum[r] = s;
    }
    __syncthreads();   // Ps visible; done reading Ks (kl)
#pragma unroll
    for (int u = 0; u < 4; u++){   // load w2 chunk into Ks
      const int f = tid + u * 256, row = f >> 4, c4 = (f & 15) << 2;
      *(float4*)&Ks[row][c4] = *(const float4*)(w2b + (size_t)(j0 + row) * DH + c4);
    }
    __syncthreads();
#pragma unroll
    for (int r = 0; r < 4; r++){
      float alpha = expf(m_run[r] - mnew[r]);
      l_run[r] = l_run[r]*alpha + psum[r];
      m_run[r] = mnew[r];
#pragma unroll
      for (int c = 0; c < 4; c++) o[r][c] *= alpha;
    }
#pragma unroll
    for (int kk = 0; kk < 64; kk++){
      float p[4], vv[4];
#pragma unroll
      for (int r = 0; r < 4; r++) p[r] = Ps[ty*4+r][kk];
#pragma unroll
      for (int c = 0; c < 4; c++) vv[c] = Ks[kk][c*16+tx];
#pragma unroll
      for (int r = 0; r < 4; r++)
#pragma unroll
        for (int c = 0; c < 4; c++) o[r][c] += p[r]*vv[c];
    }
  }
  // normalize
#pragma unroll
  for (int r = 0; r < 4; r++){
    const float inv = 1.f / l_run[r];
#pragma unroll
    for (int c = 0; c < 4; c++) o[r][c] *= inv;
  }
  // conv: stage v rows [i0-16, i0+79] (96 rows) into Vs (aliases Qs/Ks)
  __syncthreads();
#pragma unroll
  for (int u = 0; u < 6; u++){
    const int f = tid + u * 256, row = f >> 4, c4 = (f & 15) << 2;
    const int g = i0 - 16 + row;
    float4 vv = make_float4(0.f, 0.f, 0.f, 0.f);
    if (g >= 0 && g < NTOK) vv = *(const float4*)(vb + (size_t)g * DH + c4);
    *(float4*)&Vs[row][c4] = vv;
  }
  __syncthreads();
#pragma unroll 3
  for (int t = 0; t < 33; t++){
    const float w = wcs[t];
#pragma unroll
    for (int r = 0; r < 4; r++)
#pragma unroll
      for (int c = 0; c < 4; c++)
        o[r][c] += w * Vs[ty*4 + r + t][c*16 + tx];
  }
  // stage output into Ps (free now), then coalesced write over q tile
#pragma unroll
  for (int r = 0; r < 4; r++)
#pragma unroll
    for (int c = 0; c < 4; c++)
      Ps[ty*4+r][c*16+tx] = o[r][c];
  __syncthreads();
#pragma unroll
  for (int u = 0; u < 4; u++){
    const int f = tid + u * 256, row = f >> 4, c4 = (f & 15) << 2;
    *(float4*)(qb + (size_t)(i0 + row) * DH + c4) = *(const float4*)&Ps[row][c4];
  }
}

// ---------------- final: out = x + b_out + OH(gathered) @ w_out; 128x64 tile, 8x4/thread
__global__ __launch_bounds__(256) void k_final(const float* __restrict__ oh,
                                               const float* __restrict__ wout,
                                               const float* __restrict__ xin,
                                               const float* __restrict__ bout,
                                               float* __restrict__ outp){
  const int n0 = blockIdx.x * 64;    // over 512
  const int m0 = blockIdx.y * 128;   // over 16384
  __shared__ float As[16][132];
  __shared__ float Bs[16][68];
  const int tid = threadIdx.x, ty = tid >> 4, tx = tid & 15;
  const int bb = m0 >> 13;
  float acc[8][4] = {};
  for (int k0 = 0; k0 < 512; k0 += 16){
#pragma unroll
    for (int u = 0; u < 2; u++){
      const int f = tid + u * 256;
      const int row = f >> 2, kc4 = (f & 3) << 2;
      const int kidx = k0 + kc4;
      const int hh = kidx >> 6, dd = kidx & 63;
      const int i = (m0 + row) & 8191;
      float4 a4 = *(const float4*)(oh + (((size_t)(bb * NHEAD + hh)) * NTOK + i) * DH + dd);
      As[kc4+0][row] = a4.x; As[kc4+1][row] = a4.y;
      As[kc4+2][row] = a4.z; As[kc4+3][row] = a4.w;
    }
    {
      const int row = tid >> 4, c4 = (tid & 15) << 2;
      *(float4*)&Bs[row][c4] = *(const float4*)(wout + (size_t)(k0 + row) * 512 + n0 + c4);
    }
    __syncthreads();
#pragma unroll
    for (int kk = 0; kk < 16; kk++){
      float a[8], bv[4];
#pragma unroll
      for (int r = 0; r < 8; r++) a[r] = As[kk][ty*8 + r];
#pragma unroll
      for (int c = 0; c < 4; c++) bv[c] = Bs[kk][tx*4 + c];
#pragma unroll
      for (int r = 0; r < 8; r++)
#pragma unroll
        for (int c = 0; c < 4; c++) acc[r][c] += a[r] * bv[c];
    }
    __syncthreads();
  }
#pragma unroll
  for (int r = 0; r < 8; r++){
    const int row = m0 + ty*8 + r;
#pragma unroll
    for (int c = 0; c < 4; c++){
      const int col = n0 + tx*4 + c;
      outp[(size_t)row * 512 + col] = acc[r][c] + bout[col] + xin[(size_t)row * 512 + col];
    }
  }
}

extern "C" void kernel_launch(void* const* d_in, const int* in_sizes, int n_in,
                              void* d_out, int out_size, void* d_ws, size_t ws_size,
                              hipStream_t stream){
  (void)in_sizes; (void)n_in; (void)out_size; (void)ws_size;
  const float* x     = (const float*)d_in[0];
  const float* wqkv  = (const float*)d_in[1];
  const float* wout  = (const float*)d_in[2];
  const float* bout  = (const float*)d_in[3];
  const float* wconv = (const float*)d_in[4];
  float* outp = (float*)d_out;

  char* base = (char*)d_ws;
  auto alloc = [&](size_t bytes)->char*{
    char* p = base; base += (bytes + 255) & ~(size_t)255; return p;
  };
  const size_t QS = (size_t)BH * NTOK * DH;   // 8388608
  const size_t LS = (size_t)BH * MLM * DH;    // 262144
  const size_t MM = (size_t)BH * MLM * MLM;   // 1048576

  float* qf   = (float*)alloc(QS * 4);   // q (scaled); oh written in place later
  float* kf   = (float*)alloc(QS * 4);
  float* vf   = (float*)alloc(QS * 4);
  float* qlf  = (float*)alloc(LS * 4);
  float* klf  = (float*)alloc(LS * 4);
  float* a2   = (float*)alloc(MM * 4);
  float* zb   = (float*)alloc(MM * 4);
  float* z2   = (float*)alloc(MM * 4);
  float* xz   = (float*)alloc(MM * 4);
  float* t2   = (float*)alloc(MM * 4);
  float* t4   = (float*)alloc(MM * 4);
  float* part = (float*)alloc(64 * 4);
  float* pbuf = (float*)alloc((size_t)BH * 8 * 256 * 68 * 4);  // 8.9 MB
  float* av   = (float*)alloc(LS * 4);
  float* w2   = (float*)alloc(LS * 4);
  // total ~139 MB

  // 1. QKV projection
  k_qkv<<<dim3(24, 128), 256, 0, stream>>>(x, wqkv, qf, kf, vf);
  // 2. landmarks
  k_land2<<<dim3(BH * MLM, 2), 64, 0, stream>>>(qf, kf, qlf, klf);
  // 3. sim2 + softmax -> attn2
  k_sim2<<<dim3(4, 4, BH), 256, 0, stream>>>(qlf, klf, xz);
  k_softmax256<<<BH * MLM, 256, 0, stream>>>(xz, a2);
  // 4. pinv init
  k_colrow<<<BH, 256, 0, stream>>>(a2, part);
  k_z0<<<BH * MLM, 256, 0, stream>>>(a2, part, zb);
  // 5. 6 Newton-Schulz iterations (fp32)
  float* zc = zb; float* zn = z2;
  for (int it = 0; it < 6; ++it){
    k_gemm256<<<dim3(32, BH), 256, 0, stream>>>(a2, zc, a2, xz, 0.f, -1.f);   // xz = a2@z
    k_gemm256<<<dim3(32, BH), 256, 0, stream>>>(xz, xz, xz, t2, 7.f, 1.f);    // t2 = 7xz - xz@xz
    k_gemm256<<<dim3(32, BH), 256, 0, stream>>>(xz, t2, xz, t4, 15.f, 1.f);   // t4 = 15xz - xz@t2
    k_gemm256<<<dim3(32, BH), 256, 0, stream>>>(zc, t4, zc, zn, 13.f, 0.25f); // z' = .25(13z - z@t4)
    float* tmp = zc; zc = zn; zn = tmp;
  }
  // 6. flash attn3@v + combine
  k_flash<<<dim3(8, 4, BH), 256, 0, stream>>>(qlf, kf, vf, pbuf);
  k_comb<<<BH * MLM / 4, 256, 0, stream>>>(pbuf, av);
  // 7. w2 = z_final @ av
  k_w2<<<dim3(4, BH), 256, 0, stream>>>(zc, av, w2);
  // 8. fused flash attn1 + conv; oh overwrites q
  k_attn1<<<dim3(128, BH), 256, 52224, stream>>>(qf, klf, vf, w2, wconv);
  // 9. output projection + residual
  k_final<<<dim3(8, 128), 256, 0, stream>>>(qf, wout, x, bout, outp);
}

// Round 9
// 1189.178 us; speedup vs baseline: 2.5669x; 1.3246x over previous
//
#include <hip/hip_runtime.h>
#include <hip/hip_bf16.h>

#define BH 16
#define NTOK 8192
#define NHEAD 8
#define DH 64
#define MLM 256
#define QSCALE 0.125f

typedef unsigned short ushort_t;
using frag_ab = __attribute__((ext_vector_type(8))) short;   // 8 bf16 (4 VGPRs)
using frag_cd = __attribute__((ext_vector_type(4))) float;   // 4 fp32 acc

__device__ __forceinline__ unsigned short f2bs(float f){
  __hip_bfloat16 h = __float2bfloat16(f);
  return *(unsigned short*)&h;
}
__device__ __forceinline__ float bs2f(unsigned short u){
  union { unsigned int i; float f; } cv; cv.i = ((unsigned int)u) << 16; return cv.f;
}

// ---------------- weight transpose + hi/lo bf16 split: in[K][N] -> outh/outl [N][K]
__global__ __launch_bounds__(256) void k_splitw(const float* __restrict__ in, int K, int N,
                                                unsigned short* __restrict__ oh,
                                                unsigned short* __restrict__ ol){
  const int idx = blockIdx.x * 256 + threadIdx.x;   // over N*K
  const int n = idx / K, k = idx - n * K;
  const float v = in[(size_t)k * N + n];
  const unsigned short hi = f2bs(v);
  oh[idx] = hi;
  ol[idx] = f2bs(v - bs2f(hi));
}

// ---------------- MFMA split-bf16 GEMM: qkv.  A = x[16384][512] fp32 (split on the fly),
// B = wqkvT hi/lo [1536][512] bf16.  128x128 tile, 4 waves, each 64x64 (4x4 of 16x16x32).
__global__ __launch_bounds__(256) void k_mfma_qkv(const float* __restrict__ x,
                                                  const unsigned short* __restrict__ bth,
                                                  const unsigned short* __restrict__ btl,
                                                  float* __restrict__ q,
                                                  float* __restrict__ k,
                                                  float* __restrict__ v){
  const int n0 = blockIdx.x * 128;   // over 1536
  const int m0 = blockIdx.y * 128;   // over 16384
  __shared__ unsigned short Ah[128][40], Al[128][40], Bh[128][40], Bl[128][40];
  const int tid = threadIdx.x;
  const int wave = tid >> 6, lane = tid & 63;
  const int wm = wave >> 1, wn = wave & 1;
  const int lr = lane & 15, quad = lane >> 4, koff = quad * 8;
  frag_cd acc[4][4];
#pragma unroll
  for (int mt = 0; mt < 4; mt++)
#pragma unroll
    for (int nt = 0; nt < 4; nt++){
      frag_cd z = {0.f, 0.f, 0.f, 0.f};
      acc[mt][nt] = z;
    }
  for (int k0 = 0; k0 < 512; k0 += 32){
    __syncthreads();
    // stage A (fp32 -> hi/lo bf16)
#pragma unroll
    for (int u = 0; u < 4; u++){
      const int f = tid + u * 256, row = f >> 3, c4 = (f & 7) << 2;
      float4 a4 = *(const float4*)(x + (size_t)(m0 + row) * 512 + k0 + c4);
      const unsigned short h0 = f2bs(a4.x), h1 = f2bs(a4.y), h2 = f2bs(a4.z), h3 = f2bs(a4.w);
      *(ushort4*)&Ah[row][c4] = make_ushort4(h0, h1, h2, h3);
      *(ushort4*)&Al[row][c4] = make_ushort4(f2bs(a4.x - bs2f(h0)), f2bs(a4.y - bs2f(h1)),
                                             f2bs(a4.z - bs2f(h2)), f2bs(a4.w - bs2f(h3)));
    }
    // stage B (pre-split bf16)
#pragma unroll
    for (int u = 0; u < 2; u++){
      const int f = tid + u * 256, row = f >> 2, ch = (f & 3) << 3;
      *(uint4*)&Bh[row][ch] = *(const uint4*)(bth + (size_t)(n0 + row) * 512 + k0 + ch);
      *(uint4*)&Bl[row][ch] = *(const uint4*)(btl + (size_t)(n0 + row) * 512 + k0 + ch);
    }
    __syncthreads();
    frag_ab a_h[4], a_l[4], b_h[4], b_l[4];
#pragma unroll
    for (int t = 0; t < 4; t++){
      a_h[t] = *(const frag_ab*)&Ah[wm*64 + t*16 + lr][koff];
      a_l[t] = *(const frag_ab*)&Al[wm*64 + t*16 + lr][koff];
      b_h[t] = *(const frag_ab*)&Bh[wn*64 + t*16 + lr][koff];
      b_l[t] = *(const frag_ab*)&Bl[wn*64 + t*16 + lr][koff];
    }
#pragma unroll
    for (int mt = 0; mt < 4; mt++)
#pragma unroll
      for (int nt = 0; nt < 4; nt++){
        acc[mt][nt] = __builtin_amdgcn_mfma_f32_16x16x32_bf16(a_l[mt], b_h[nt], acc[mt][nt], 0, 0, 0);
        acc[mt][nt] = __builtin_amdgcn_mfma_f32_16x16x32_bf16(a_h[mt], b_l[nt], acc[mt][nt], 0, 0, 0);
        acc[mt][nt] = __builtin_amdgcn_mfma_f32_16x16x32_bf16(a_h[mt], b_h[nt], acc[mt][nt], 0, 0, 0);
      }
  }
  // epilogue: D row = quad*4+reg, col = lane&15
#pragma unroll
  for (int mt = 0; mt < 4; mt++)
#pragma unroll
    for (int nt = 0; nt < 4; nt++)
#pragma unroll
      for (int rg = 0; rg < 4; rg++){
        const int row = m0 + wm*64 + mt*16 + quad*4 + rg;
        const int col = n0 + wn*64 + nt*16 + lr;
        const int bb = row >> 13, i = row & 8191;
        const int which = col >> 9;
        const int cc = col & 511;
        const int h = cc >> 6, d = cc & 63;
        const size_t off = (((size_t)(bb * NHEAD + h)) * NTOK + i) * DH + d;
        const float val = acc[mt][nt][rg];
        if (which == 0)      q[off] = val * QSCALE;
        else if (which == 1) k[off] = val;
        else                 v[off] = val;
      }
}

// ---------------- MFMA split-bf16 GEMM: final.  A = oh packed (hi|lo in uint32 slots of qf,
// layout [bh][8192][64]), B = woutT hi/lo [512][512].  out = A@B + bout + x.
__global__ __launch_bounds__(256) void k_mfma_final(const unsigned int* __restrict__ qpk,
                                                    const unsigned short* __restrict__ bth,
                                                    const unsigned short* __restrict__ btl,
                                                    const float* __restrict__ xin,
                                                    const float* __restrict__ bout,
                                                    float* __restrict__ outp){
  const int n0 = blockIdx.x * 128;   // over 512
  const int m0 = blockIdx.y * 128;   // over 16384
  __shared__ unsigned short Ah[128][40], Al[128][40], Bh[128][40], Bl[128][40];
  const int tid = threadIdx.x;
  const int wave = tid >> 6, lane = tid & 63;
  const int wm = wave >> 1, wn = wave & 1;
  const int lr = lane & 15, quad = lane >> 4, koff = quad * 8;
  const int bb = m0 >> 13;
  frag_cd acc[4][4];
#pragma unroll
  for (int mt = 0; mt < 4; mt++)
#pragma unroll
    for (int nt = 0; nt < 4; nt++){
      frag_cd z = {0.f, 0.f, 0.f, 0.f};
      acc[mt][nt] = z;
    }
  for (int k0 = 0; k0 < 512; k0 += 32){
    const int h = k0 >> 6, dbase = k0 & 63;
    __syncthreads();
    // stage A from packed hi|lo uint32
#pragma unroll
    for (int u = 0; u < 4; u++){
      const int f = tid + u * 256, row = f >> 3, c4 = (f & 7) << 2;
      const int i = (m0 + row) & 8191;
      uint4 pw = *(const uint4*)(qpk + (((size_t)(bb * NHEAD + h)) * NTOK + i) * DH + dbase + c4);
      *(ushort4*)&Ah[row][c4] = make_ushort4((unsigned short)pw.x, (unsigned short)pw.y,
                                             (unsigned short)pw.z, (unsigned short)pw.w);
      *(ushort4*)&Al[row][c4] = make_ushort4((unsigned short)(pw.x >> 16), (unsigned short)(pw.y >> 16),
                                             (unsigned short)(pw.z >> 16), (unsigned short)(pw.w >> 16));
    }
#pragma unroll
    for (int u = 0; u < 2; u++){
      const int f = tid + u * 256, row = f >> 2, ch = (f & 3) << 3;
      *(uint4*)&Bh[row][ch] = *(const uint4*)(bth + (size_t)(n0 + row) * 512 + k0 + ch);
      *(uint4*)&Bl[row][ch] = *(const uint4*)(btl + (size_t)(n0 + row) * 512 + k0 + ch);
    }
    __syncthreads();
    frag_ab a_h[4], a_l[4], b_h[4], b_l[4];
#pragma unroll
    for (int t = 0; t < 4; t++){
      a_h[t] = *(const frag_ab*)&Ah[wm*64 + t*16 + lr][koff];
      a_l[t] = *(const frag_ab*)&Al[wm*64 + t*16 + lr][koff];
      b_h[t] = *(const frag_ab*)&Bh[wn*64 + t*16 + lr][koff];
      b_l[t] = *(const frag_ab*)&Bl[wn*64 + t*16 + lr][koff];
    }
#pragma unroll
    for (int mt = 0; mt < 4; mt++)
#pragma unroll
      for (int nt = 0; nt < 4; nt++){
        acc[mt][nt] = __builtin_amdgcn_mfma_f32_16x16x32_bf16(a_l[mt], b_h[nt], acc[mt][nt], 0, 0, 0);
        acc[mt][nt] = __builtin_amdgcn_mfma_f32_16x16x32_bf16(a_h[mt], b_l[nt], acc[mt][nt], 0, 0, 0);
        acc[mt][nt] = __builtin_amdgcn_mfma_f32_16x16x32_bf16(a_h[mt], b_h[nt], acc[mt][nt], 0, 0, 0);
      }
  }
#pragma unroll
  for (int mt = 0; mt < 4; mt++)
#pragma unroll
    for (int nt = 0; nt < 4; nt++)
#pragma unroll
      for (int rg = 0; rg < 4; rg++){
        const int row = m0 + wm*64 + mt*16 + quad*4 + rg;
        const int col = n0 + wn*64 + nt*16 + lr;
        outp[(size_t)row * 512 + col] = acc[mt][nt][rg] + bout[col] + xin[(size_t)row * 512 + col];
      }
}

// ---------------- landmark means for q and k in one launch (grid.y selects)
__global__ __launch_bounds__(64) void k_land2(const float* __restrict__ qf, const float* __restrict__ kf,
                                              float* __restrict__ qlf, float* __restrict__ klf){
  const float* src = blockIdx.y ? kf : qf;
  float* dst = blockIdx.y ? klf : qlf;
  const int bh = blockIdx.x >> 8;
  const int j  = blockIdx.x & 255;
  const int d  = threadIdx.x;
  const float* p = src + ((size_t)bh * NTOK + (size_t)j * 32) * DH + d;
  float s = 0.f;
#pragma unroll
  for (int t = 0; t < 32; t++) s += p[t * DH];
  dst[((size_t)bh * MLM + j) * DH + d] = s * (1.f / 32.f);
}

// ---------------- sim2 = ql @ kl^T (fp32, K=64), batched [bh][256][256]
__global__ __launch_bounds__(256) void k_sim2(const float* __restrict__ qlf,
                                              const float* __restrict__ klf,
                                              float* __restrict__ C){
  const int bh = blockIdx.z;
  const float* Ab = qlf + (size_t)bh * MLM * DH;
  const float* Bb = klf + (size_t)bh * MLM * DH;
  float* Cb = C + (size_t)bh * MLM * MLM;
  const int n0 = blockIdx.x * 64;
  const int m0 = blockIdx.y * 64;
  __shared__ float As[16][64];
  __shared__ float Bs[16][64];
  const int tid = threadIdx.x, ty = tid >> 4, tx = tid & 15;
  const int lm = tid >> 2, lk = (tid & 3) << 2;
  float acc[4][4] = {};
  for (int k0 = 0; k0 < 64; k0 += 16){
    float4 a4 = *(const float4*)(Ab + (size_t)(m0 + lm) * DH + k0 + lk);
    As[lk+0][lm] = a4.x; As[lk+1][lm] = a4.y; As[lk+2][lm] = a4.z; As[lk+3][lm] = a4.w;
    float4 b4 = *(const float4*)(Bb + (size_t)(n0 + lm) * DH + k0 + lk);
    Bs[lk+0][lm] = b4.x; Bs[lk+1][lm] = b4.y; Bs[lk+2][lm] = b4.z; Bs[lk+3][lm] = b4.w;
    __syncthreads();
#pragma unroll
    for (int kk = 0; kk < 16; kk++){
      float a[4], bv[4];
#pragma unroll
      for (int r = 0; r < 4; r++) a[r] = As[kk][ty*4 + r];
#pragma unroll
      for (int c = 0; c < 4; c++) bv[c] = Bs[kk][tx*4 + c];
#pragma unroll
      for (int r = 0; r < 4; r++)
#pragma unroll
        for (int c = 0; c < 4; c++) acc[r][c] += a[r] * bv[c];
    }
    __syncthreads();
  }
#pragma unroll
  for (int r = 0; r < 4; r++)
#pragma unroll
    for (int c = 0; c < 4; c++)
      Cb[(size_t)(m0 + ty*4 + r) * MLM + n0 + tx*4 + c] = acc[r][c];
}

// ---------------- row softmax over 256
__global__ __launch_bounds__(256) void k_softmax256(const float* __restrict__ in, float* __restrict__ outp){
  const int row = blockIdx.x;
  const int t = threadIdx.x;
  float v = in[(size_t)row * 256 + t];
  __shared__ float red[256];
  red[t] = v; __syncthreads();
  for (int o = 128; o > 0; o >>= 1){ if (t < o) red[t] = fmaxf(red[t], red[t+o]); __syncthreads(); }
  float mx = red[0]; __syncthreads();
  float e = expf(v - mx);
  red[t] = e; __syncthreads();
  for (int o = 128; o > 0; o >>= 1){ if (t < o) red[t] += red[t+o]; __syncthreads(); }
  outp[(size_t)row * 256 + t] = e / red[0];
}

// ---------------- per-batch row/col abs-sum maxima partials
__global__ __launch_bounds__(256) void k_colrow(const float* __restrict__ a2, float* __restrict__ part){
  const int bh = blockIdx.x;
  const int t = threadIdx.x;
  const float* p = a2 + (size_t)bh * 65536;
  float rs = 0.f, cs = 0.f;
  for (int j = 0; j < 256; j++) rs += fabsf(p[(size_t)t * 256 + j]);
  for (int i = 0; i < 256; i++) cs += fabsf(p[(size_t)i * 256 + t]);
  __shared__ float r1[256], r2[256];
  r1[t] = rs; r2[t] = cs; __syncthreads();
  for (int o = 128; o > 0; o >>= 1){
    if (t < o){ r1[t] = fmaxf(r1[t], r1[t+o]); r2[t] = fmaxf(r2[t], r2[t+o]); }
    __syncthreads();
  }
  if (t == 0){ part[bh] = r1[0]; part[16 + bh] = r2[0]; }
}

// ---------------- z0 = a2^T * (1/(col*row)), GLOBAL maxima over all bh
__global__ __launch_bounds__(256) void k_z0(const float* __restrict__ a2, const float* __restrict__ part,
                                            float* __restrict__ z){
  const int bh = blockIdx.x >> 8;
  const int i  = blockIdx.x & 255;
  const int j  = threadIdx.x;
  float m1 = 0.f, m2 = 0.f;
#pragma unroll
  for (int t = 0; t < 16; t++){ m1 = fmaxf(m1, part[t]); m2 = fmaxf(m2, part[16 + t]); }
  const float sc = 1.f / (m1 * m2);
  z[((size_t)bh * 256 + i) * 256 + j] = a2[((size_t)bh * 256 + j) * 256 + i] * sc;
}

// ---------------- batched 256^3 GEMM with pinv epilogue: C = s0*(c0*D - A@B)
__global__ __launch_bounds__(256) void k_gemm256(const float* __restrict__ A, const float* __restrict__ Bm,
                                                 const float* __restrict__ D, float* __restrict__ C,
                                                 float c0, float s0){
  const int bh = blockIdx.y;
  const int mt = blockIdx.x >> 2, nt = blockIdx.x & 3;
  const size_t bo = (size_t)bh * 65536;
  const float* Ab = A + bo; const float* Bb = Bm + bo;
  const float* Db = D + bo; float* Cb = C + bo;
  __shared__ float As[16][33];
  __shared__ float Bs[16][66];
  const int tid = threadIdx.x, ty = tid >> 5, tx = tid & 31;
  const int m0 = mt * 32, n0 = nt * 64;
  float acc[4][2] = {};
  for (int k0 = 0; k0 < 256; k0 += 16){
    if (tid < 128){
      const int row = tid >> 2, kc4 = (tid & 3) << 2;
      float4 a4 = *(const float4*)(Ab + (size_t)(m0 + row) * 256 + k0 + kc4);
      As[kc4+0][row] = a4.x; As[kc4+1][row] = a4.y;
      As[kc4+2][row] = a4.z; As[kc4+3][row] = a4.w;
    }
    {
      const int row = tid >> 4, c4 = (tid & 15) << 2;
      *(float4*)&Bs[row][c4] = *(const float4*)(Bb + (size_t)(k0 + row) * 256 + n0 + c4);
    }
    __syncthreads();
#pragma unroll
    for (int kk = 0; kk < 16; kk++){
      float a[4], bv[2];
#pragma unroll
      for (int r = 0; r < 4; r++) a[r] = As[kk][ty*4 + r];
      bv[0] = Bs[kk][tx*2]; bv[1] = Bs[kk][tx*2 + 1];
#pragma unroll
      for (int r = 0; r < 4; r++){
        acc[r][0] += a[r] * bv[0];
        acc[r][1] += a[r] * bv[1];
      }
    }
    __syncthreads();
  }
#pragma unroll
  for (int r = 0; r < 4; r++)
#pragma unroll
    for (int c = 0; c < 2; c++){
      const size_t idx = (size_t)(m0 + ty*4 + r) * 256 + n0 + tx*2 + c;
      Cb[idx] = s0 * (c0 * Db[idx] - acc[r][c]);
    }
}

// ---------------- flash: partial online-softmax (attn3 @ v) per (kc, mtile, bh), fp32
__global__ __launch_bounds__(256) void k_flash(const float* __restrict__ ql,
                                               const float* __restrict__ kmat,
                                               const float* __restrict__ vmat,
                                               float* __restrict__ pbuf){
  const int kc = blockIdx.x;
  const int mt = blockIdx.y;
  const int bh = blockIdx.z;
  const int m0 = mt * 64;
  const int kbeg = kc * 1024;
  const float* qlb = ql + (size_t)bh * MLM * DH;
  const float* kb  = kmat + (size_t)bh * NTOK * DH;
  const float* vb  = vmat + (size_t)bh * NTOK * DH;
  __shared__ float Qs[64][68];
  __shared__ float Ks[64][68];
  __shared__ float Ps[64][68];
  const int tid = threadIdx.x, ty = tid >> 4, tx = tid & 15;
#pragma unroll
  for (int u = 0; u < 4; u++){
    const int f = tid + u * 256, row = f >> 4, c4 = (f & 15) << 2;
    *(float4*)&Qs[row][c4] = *(const float4*)(qlb + (size_t)(m0 + row) * DH + c4);
  }
  float m_run[4], l_run[4], o[4][4];
#pragma unroll
  for (int r = 0; r < 4; r++){
    m_run[r] = -1e30f; l_run[r] = 0.f;
#pragma unroll
    for (int c = 0; c < 4; c++) o[r][c] = 0.f;
  }
  for (int ch = 0; ch < 16; ch++){
    const int kr0 = kbeg + ch * 64;
    __syncthreads();
#pragma unroll
    for (int u = 0; u < 4; u++){
      const int f = tid + u * 256, row = f >> 4, c4 = (f & 15) << 2;
      *(float4*)&Ks[row][c4] = *(const float4*)(kb + (size_t)(kr0 + row) * DH + c4);
    }
    __syncthreads();
    float S[4][4] = {};
#pragma unroll
    for (int kk = 0; kk < 64; kk++){
      float a[4], bvv[4];
#pragma unroll
      for (int r = 0; r < 4; r++) a[r] = Qs[ty*4+r][kk];
#pragma unroll
      for (int c = 0; c < 4; c++) bvv[c] = Ks[c*16+tx][kk];
#pragma unroll
      for (int r = 0; r < 4; r++)
#pragma unroll
        for (int c = 0; c < 4; c++) S[r][c] += a[r]*bvv[c];
    }
    float mnew[4], psum[4];
#pragma unroll
    for (int r = 0; r < 4; r++){
      float mx = fmaxf(fmaxf(S[r][0],S[r][1]),fmaxf(S[r][2],S[r][3]));
#pragma unroll
      for (int o2 = 8; o2 >= 1; o2 >>= 1) mx = fmaxf(mx, __shfl_xor(mx, o2));
      mnew[r] = fmaxf(m_run[r], mx);
      float e0=expf(S[r][0]-mnew[r]), e1=expf(S[r][1]-mnew[r]),
            e2=expf(S[r][2]-mnew[r]), e3=expf(S[r][3]-mnew[r]);
      Ps[ty*4+r][0*16+tx]=e0; Ps[ty*4+r][1*16+tx]=e1;
      Ps[ty*4+r][2*16+tx]=e2; Ps[ty*4+r][3*16+tx]=e3;
      float s = e0+e1+e2+e3;
#pragma unroll
      for (int o2 = 8; o2 >= 1; o2 >>= 1) s += __shfl_xor(s, o2);
      psum[r] = s;
    }
    __syncthreads();
#pragma unroll
    for (int u = 0; u < 4; u++){
      const int f = tid + u * 256, row = f >> 4, c4 = (f & 15) << 2;
      *(float4*)&Ks[row][c4] = *(const float4*)(vb + (size_t)(kr0 + row) * DH + c4);
    }
    __syncthreads();
#pragma unroll
    for (int r = 0; r < 4; r++){
      float alpha = expf(m_run[r] - mnew[r]);
      l_run[r] = l_run[r]*alpha + psum[r];
      m_run[r] = mnew[r];
#pragma unroll
      for (int c = 0; c < 4; c++) o[r][c] *= alpha;
    }
#pragma unroll
    for (int kk = 0; kk < 64; kk++){
      float p[4], vv[4];
#pragma unroll
      for (int r = 0; r < 4; r++) p[r] = Ps[ty*4+r][kk];
#pragma unroll
      for (int c = 0; c < 4; c++) vv[c] = Ks[kk][c*16+tx];
#pragma unroll
      for (int r = 0; r < 4; r++)
#pragma unroll
        for (int c = 0; c < 4; c++) o[r][c] += p[r]*vv[c];
    }
  }
  __syncthreads();
#pragma unroll
  for (int r = 0; r < 4; r++){
#pragma unroll
    for (int c = 0; c < 4; c++) Ps[ty*4+r][c*16+tx] = o[r][c];
    if (tx == 0){ Ps[ty*4+r][64] = m_run[r]; Ps[ty*4+r][65] = l_run[r]; }
  }
  __syncthreads();
  float* pb = pbuf + (((size_t)bh * 8 + kc) * 256 + m0) * 68;
  for (int f = tid; f < 1088; f += 256){
    const int row = f / 17, g = f % 17;
    *(float4*)(pb + (size_t)row * 68 + g*4) = *(const float4*)&Ps[row][g*4];
  }
}

// ---------------- combine flash partials -> av fp32 [bh][256][64]
__global__ __launch_bounds__(256) void k_comb(const float* __restrict__ pbuf, float* __restrict__ av){
  const int wv = threadIdx.x >> 6, lane = threadIdx.x & 63;
  const int id = blockIdx.x * 4 + wv;
  const int bh = id >> 8, row = id & 255;
  const float* base = pbuf + ((size_t)bh * 8 * 256 + row) * 68;
  float M = -1e30f;
#pragma unroll
  for (int k = 0; k < 8; k++) M = fmaxf(M, base[(size_t)k * 256 * 68 + 64]);
  float L = 0.f, o = 0.f;
#pragma unroll
  for (int k = 0; k < 8; k++){
    const float* p = base + (size_t)k * 256 * 68;
    float w = expf(p[64] - M);
    L += p[65] * w;
    o += p[lane] * w;
  }
  av[((size_t)bh * MLM + row) * DH + lane] = o / L;
}

// ---------------- w2 = z_final @ av (fp32, M=256,N=64,K=256), batched
__global__ __launch_bounds__(256) void k_w2(const float* __restrict__ Z, const float* __restrict__ AV,
                                            float* __restrict__ W2){
  const int bh = blockIdx.y, mt = blockIdx.x;
  const float* Zb = Z + (size_t)bh * 65536;
  const float* Vb = AV + (size_t)bh * MLM * DH;
  float* Wb = W2 + (size_t)bh * MLM * DH;
  const int m0 = mt * 64;
  __shared__ float As[16][64];
  __shared__ float Bs[16][64];
  const int tid = threadIdx.x, ty = tid >> 4, tx = tid & 15;
  const int lm = tid >> 2, lk = (tid & 3) << 2;
  const int lk2 = tid >> 4, ln = (tid & 15) << 2;
  float acc[4][4] = {};
  for (int k0 = 0; k0 < 256; k0 += 16){
    float4 a4 = *(const float4*)(Zb + (size_t)(m0 + lm) * 256 + k0 + lk);
    As[lk+0][lm] = a4.x; As[lk+1][lm] = a4.y; As[lk+2][lm] = a4.z; As[lk+3][lm] = a4.w;
    float4 b4 = *(const float4*)(Vb + (size_t)(k0 + lk2) * DH + ln);
    *(float4*)&Bs[lk2][ln] = b4;
    __syncthreads();
#pragma unroll
    for (int kk = 0; kk < 16; kk++){
      float a[4], bv[4];
#pragma unroll
      for (int r = 0; r < 4; r++) a[r] = As[kk][ty*4 + r];
#pragma unroll
      for (int c = 0; c < 4; c++) bv[c] = Bs[kk][tx*4 + c];
#pragma unroll
      for (int r = 0; r < 4; r++)
#pragma unroll
        for (int c = 0; c < 4; c++) acc[r][c] += a[r] * bv[c];
    }
    __syncthreads();
  }
#pragma unroll
  for (int r = 0; r < 4; r++)
#pragma unroll
    for (int c = 0; c < 4; c++)
      Wb[(size_t)(m0 + ty*4 + r) * DH + tx*4 + c] = acc[r][c];
}

// ---------------- fused attn1: flash over 4 landmark chunks + conv, 64-token tiles.
// Output packed as (hi|lo) bf16 pair per fp32 slot, IN PLACE over q (block-local tiles).
__global__ __launch_bounds__(256) void k_attn1(float* __restrict__ qoh,
                                               const float* __restrict__ klf,
                                               const float* __restrict__ vf,
                                               const float* __restrict__ w2,
                                               const float* __restrict__ wconv){
  extern __shared__ float smem[];
  float (*Qs)[68] = (float (*)[68])smem;
  float (*Ks)[68] = (float (*)[68])(smem + 64*68);
  float (*Ps)[68] = (float (*)[68])(smem + 2*64*68);
  float (*Vs)[68] = (float (*)[68])smem;
  __shared__ float wcs[33];
  const int it = blockIdx.x;
  const int bh = blockIdx.y;
  const int h  = bh & 7;
  const int i0 = it * 64;
  float* qb = qoh + (size_t)bh * NTOK * DH;
  const float* klb = klf + (size_t)bh * MLM * DH;
  const float* vb  = vf + (size_t)bh * NTOK * DH;
  const float* w2b = w2 + (size_t)bh * MLM * DH;
  const int tid = threadIdx.x, ty = tid >> 4, tx = tid & 15;
  if (tid < 33) wcs[tid] = wconv[h*33 + tid];
#pragma unroll
  for (int u = 0; u < 4; u++){
    const int f = tid + u * 256, row = f >> 4, c4 = (f & 15) << 2;
    *(float4*)&Qs[row][c4] = *(const float4*)(qb + (size_t)(i0 + row) * DH + c4);
  }
  float m_run[4], l_run[4], o[4][4];
#pragma unroll
  for (int r = 0; r < 4; r++){
    m_run[r] = -1e30f; l_run[r] = 0.f;
#pragma unroll
    for (int c = 0; c < 4; c++) o[r][c] = 0.f;
  }
  for (int jc = 0; jc < 4; jc++){
    const int j0 = jc * 64;
    __syncthreads();
#pragma unroll
    for (int u = 0; u < 4; u++){
      const int f = tid + u * 256, row = f >> 4, c4 = (f & 15) << 2;
      *(float4*)&Ks[row][c4] = *(const float4*)(klb + (size_t)(j0 + row) * DH + c4);
    }
    __syncthreads();
    float S[4][4] = {};
#pragma unroll
    for (int kk = 0; kk < 64; kk++){
      float a[4], bvv[4];
#pragma unroll
      for (int r = 0; r < 4; r++) a[r] = Qs[ty*4+r][kk];
#pragma unroll
      for (int c = 0; c < 4; c++) bvv[c] = Ks[c*16+tx][kk];
#pragma unroll
      for (int r = 0; r < 4; r++)
#pragma unroll
        for (int c = 0; c < 4; c++) S[r][c] += a[r]*bvv[c];
    }
    float mnew[4], psum[4];
#pragma unroll
    for (int r = 0; r < 4; r++){
      float mx = fmaxf(fmaxf(S[r][0],S[r][1]),fmaxf(S[r][2],S[r][3]));
#pragma unroll
      for (int o2 = 8; o2 >= 1; o2 >>= 1) mx = fmaxf(mx, __shfl_xor(mx, o2));
      mnew[r] = fmaxf(m_run[r], mx);
      float e0=expf(S[r][0]-mnew[r]), e1=expf(S[r][1]-mnew[r]),
            e2=expf(S[r][2]-mnew[r]), e3=expf(S[r][3]-mnew[r]);
      Ps[ty*4+r][0*16+tx]=e0; Ps[ty*4+r][1*16+tx]=e1;
      Ps[ty*4+r][2*16+tx]=e2; Ps[ty*4+r][3*16+tx]=e3;
      float s = e0+e1+e2+e3;
#pragma unroll
      for (int o2 = 8; o2 >= 1; o2 >>= 1) s += __shfl_xor(s, o2);
      psum[r] = s;
    }
    __syncthreads();
#pragma unroll
    for (int u = 0; u < 4; u++){
      const int f = tid + u * 256, row = f >> 4, c4 = (f & 15) << 2;
      *(float4*)&Ks[row][c4] = *(const float4*)(w2b + (size_t)(j0 + row) * DH + c4);
    }
    __syncthreads();
#pragma unroll
    for (int r = 0; r < 4; r++){
      float alpha = expf(m_run[r] - mnew[r]);
      l_run[r] = l_run[r]*alpha + psum[r];
      m_run[r] = mnew[r];
#pragma unroll
      for (int c = 0; c < 4; c++) o[r][c] *= alpha;
    }
#pragma unroll
    for (int kk = 0; kk < 64; kk++){
      float p[4], vv[4];
#pragma unroll
      for (int r = 0; r < 4; r++) p[r] = Ps[ty*4+r][kk];
#pragma unroll
      for (int c = 0; c < 4; c++) vv[c] = Ks[kk][c*16+tx];
#pragma unroll
      for (int r = 0; r < 4; r++)
#pragma unroll
        for (int c = 0; c < 4; c++) o[r][c] += p[r]*vv[c];
    }
  }
#pragma unroll
  for (int r = 0; r < 4; r++){
    const float inv = 1.f / l_run[r];
#pragma unroll
    for (int c = 0; c < 4; c++) o[r][c] *= inv;
  }
  // conv: stage v rows [i0-16, i0+79] (96 rows) into Vs (aliases Qs/Ks)
  __syncthreads();
#pragma unroll
  for (int u = 0; u < 6; u++){
    const int f = tid + u * 256, row = f >> 4, c4 = (f & 15) << 2;
    const int g = i0 - 16 + row;
    float4 vv = make_float4(0.f, 0.f, 0.f, 0.f);
    if (g >= 0 && g < NTOK) vv = *(const float4*)(vb + (size_t)g * DH + c4);
    *(float4*)&Vs[row][c4] = vv;
  }
  __syncthreads();
#pragma unroll 3
  for (int t = 0; t < 33; t++){
    const float w = wcs[t];
#pragma unroll
    for (int r = 0; r < 4; r++)
#pragma unroll
      for (int c = 0; c < 4; c++)
        o[r][c] += w * Vs[ty*4 + r + t][c*16 + tx];
  }
  // pack (hi|lo) bf16 into the fp32 slots, stage via Ps, coalesced write over q tile
#pragma unroll
  for (int r = 0; r < 4; r++)
#pragma unroll
    for (int c = 0; c < 4; c++){
      const float val = o[r][c];
      const unsigned short hi = f2bs(val);
      const unsigned short lo = f2bs(val - bs2f(hi));
      const unsigned int pk = (unsigned int)hi | ((unsigned int)lo << 16);
      Ps[ty*4+r][c*16+tx] = __uint_as_float(pk);
    }
  __syncthreads();
#pragma unroll
  for (int u = 0; u < 4; u++){
    const int f = tid + u * 256, row = f >> 4, c4 = (f & 15) << 2;
    *(float4*)(qb + (size_t)(i0 + row) * DH + c4) = *(const float4*)&Ps[row][c4];
  }
}

extern "C" void kernel_launch(void* const* d_in, const int* in_sizes, int n_in,
                              void* d_out, int out_size, void* d_ws, size_t ws_size,
                              hipStream_t stream){
  (void)in_sizes; (void)n_in; (void)out_size; (void)ws_size;
  const float* x     = (const float*)d_in[0];
  const float* wqkv  = (const float*)d_in[1];
  const float* wout  = (const float*)d_in[2];
  const float* bout  = (const float*)d_in[3];
  const float* wconv = (const float*)d_in[4];
  float* outp = (float*)d_out;

  char* base = (char*)d_ws;
  auto alloc = [&](size_t bytes)->char*{
    char* p = base; base += (bytes + 255) & ~(size_t)255; return p;
  };
  const size_t QS = (size_t)BH * NTOK * DH;   // 8388608
  const size_t LS = (size_t)BH * MLM * DH;    // 262144
  const size_t MM = (size_t)BH * MLM * MLM;   // 1048576

  float* qf   = (float*)alloc(QS * 4);   // q; packed oh overwrites in place
  float* kf   = (float*)alloc(QS * 4);
  float* vf   = (float*)alloc(QS * 4);
  float* qlf  = (float*)alloc(LS * 4);
  float* klf  = (float*)alloc(LS * 4);
  float* a2   = (float*)alloc(MM * 4);
  float* zb   = (float*)alloc(MM * 4);
  float* z2   = (float*)alloc(MM * 4);
  float* xz   = (float*)alloc(MM * 4);
  float* t2   = (float*)alloc(MM * 4);
  float* t4   = (float*)alloc(MM * 4);
  float* part = (float*)alloc(64 * 4);
  float* pbuf = (float*)alloc((size_t)BH * 8 * 256 * 68 * 4);
  float* av   = (float*)alloc(LS * 4);
  float* w2   = (float*)alloc(LS * 4);
  unsigned short* wqTh = (unsigned short*)alloc((size_t)1536 * 512 * 2);
  unsigned short* wqTl = (unsigned short*)alloc((size_t)1536 * 512 * 2);
  unsigned short* woTh = (unsigned short*)alloc((size_t)512 * 512 * 2);
  unsigned short* woTl = (unsigned short*)alloc((size_t)512 * 512 * 2);
  // total ~143 MB

  // 0. weight transpose + split
  k_splitw<<<1536 * 512 / 256, 256, 0, stream>>>(wqkv, 512, 1536, wqTh, wqTl);
  k_splitw<<<512 * 512 / 256, 256, 0, stream>>>(wout, 512, 512, woTh, woTl);
  // 1. QKV projection (MFMA split-bf16)
  k_mfma_qkv<<<dim3(12, 128), 256, 0, stream>>>(x, wqTh, wqTl, qf, kf, vf);
  // 2. landmarks
  k_land2<<<dim3(BH * MLM, 2), 64, 0, stream>>>(qf, kf, qlf, klf);
  // 3. sim2 + softmax -> attn2
  k_sim2<<<dim3(4, 4, BH), 256, 0, stream>>>(qlf, klf, xz);
  k_softmax256<<<BH * MLM, 256, 0, stream>>>(xz, a2);
  // 4. pinv init
  k_colrow<<<BH, 256, 0, stream>>>(a2, part);
  k_z0<<<BH * MLM, 256, 0, stream>>>(a2, part, zb);
  // 5. 6 Newton-Schulz iterations (fp32)
  float* zc = zb; float* zn = z2;
  for (int it = 0; it < 6; ++it){
    k_gemm256<<<dim3(32, BH), 256, 0, stream>>>(a2, zc, a2, xz, 0.f, -1.f);
    k_gemm256<<<dim3(32, BH), 256, 0, stream>>>(xz, xz, xz, t2, 7.f, 1.f);
    k_gemm256<<<dim3(32, BH), 256, 0, stream>>>(xz, t2, xz, t4, 15.f, 1.f);
    k_gemm256<<<dim3(32, BH), 256, 0, stream>>>(zc, t4, zc, zn, 13.f, 0.25f);
    float* tmp = zc; zc = zn; zn = tmp;
  }
  // 6. flash attn3@v + combine
  k_flash<<<dim3(8, 4, BH), 256, 0, stream>>>(qlf, kf, vf, pbuf);
  k_comb<<<BH * MLM / 4, 256, 0, stream>>>(pbuf, av);
  // 7. w2 = z_final @ av
  k_w2<<<dim3(4, BH), 256, 0, stream>>>(zc, av, w2);
  // 8. fused flash attn1 + conv; packed oh overwrites q
  k_attn1<<<dim3(128, BH), 256, 52224, stream>>>(qf, klf, vf, w2, wconv);
  // 9. output projection + residual (MFMA split-bf16)
  k_mfma_final<<<dim3(4, 128), 256, 0, stream>>>((const unsigned int*)qf, woTh, woTl, x, bout, outp);
}